// Round 4
// baseline (201.578 us; speedup 1.0000x reference)
//
#include <hip/hip_runtime.h>
#include <stdint.h>

// Problem constants
constexpr int NBATCH = 4;
constexpr int CH     = 256;   // channels
constexpr int LEN    = 4096;  // sequence length
constexpr int LPOOL  = 1024;  // pooled length (LEN/4)
constexpr int NH     = 4;     // heads
constexpr int HD     = 64;    // head dim

typedef __attribute__((ext_vector_type(8))) short short8;     // 8 bf16 in 4 VGPRs
typedef __attribute__((ext_vector_type(4))) float float4e;    // MFMA C/D 16x16
typedef __attribute__((ext_vector_type(16))) float float16e;  // MFMA C/D 32x32
typedef __attribute__((ext_vector_type(2))) unsigned uint2v;

__device__ __forceinline__ unsigned short f2bf(float f) {
    union { unsigned int i; float f; } v; v.f = f;
    unsigned int lsb = (v.i >> 16) & 1u;
    v.i += 0x7fffu + lsb;
    return (unsigned short)(v.i >> 16);
}
// pack two floats -> two bf16 (round-half-up via +0x8000, then byte-perm)
__device__ __forceinline__ unsigned pack2bf(float lo, float hi) {
    unsigned a = __float_as_uint(lo) + 0x8000u;
    unsigned b = __float_as_uint(hi) + 0x8000u;
    return __builtin_amdgcn_perm(b, a, 0x07060302u);
}
// single-instruction 2^x (OCML exp2f without fast-math is ~12 VALU ops)
__device__ __forceinline__ float fast_exp2(float x) {
#if __has_builtin(__builtin_amdgcn_exp2f)
    return __builtin_amdgcn_exp2f(x);
#else
    float r;
    asm("v_exp_f32 %0, %1" : "=v"(r) : "v"(x));
    return r;
#endif
}

// ---------------------------------------------------------------------------
// Fused: blocks 0..1023 do transpose+pool over x; blocks 1024..1343 cast the
// 5 weight matrices to bf16; block 1344 computes BN affine + bkv concat.
__global__ __launch_bounds__(256) void transpool_setup(
    const float* __restrict__ x, unsigned short* __restrict__ xbf,
    unsigned short* __restrict__ poolT,
    const float* __restrict__ w0, const float* __restrict__ w1,
    const float* __restrict__ w2, const float* __restrict__ w3,
    const float* __restrict__ w4, unsigned short* __restrict__ outW,
    const float* __restrict__ g1, const float* __restrict__ b1,
    const float* __restrict__ m1, const float* __restrict__ v1,
    const float* __restrict__ g2, const float* __restrict__ b2,
    const float* __restrict__ m2, const float* __restrict__ v2,
    float* __restrict__ scale, float* __restrict__ shift,
    const float* __restrict__ bk, const float* __restrict__ bv,
    float* __restrict__ bkv)
{
    __shared__ float T[64][65];
    __shared__ float P16[64][17];
    int b = blockIdx.x, t = threadIdx.x;
    if (b >= 1024) {
        int sb = b - 1024;
        if (sb < 320) {
            int gid = sb * 256 + t;
            int w = gid >> 14;
            int off = (gid & 16383) * 4;
            const float* src = (w == 0) ? w0 : (w == 1) ? w1 : (w == 2) ? w2 : (w == 3) ? w3 : w4;
            float4 v = *(const float4*)(src + off);
            uint2 pk;
            pk.x = pack2bf(v.x, v.y);
            pk.y = pack2bf(v.z, v.w);
            *(uint2*)(outW + w * 65536 + off) = pk;
        } else {
            float inv1 = g1[t] * rsqrtf(v1[t] + 1e-5f);
            float inv2 = g2[t] * rsqrtf(v2[t] + 1e-5f);
            scale[t] = inv1 * inv2;
            shift[t] = (b1[t] - m1[t] * inv1) * inv2 + (b2[t] - m2[t] * inv2);
            bkv[t] = bk[t];
            bkv[256 + t] = bv[t];
        }
        return;
    }
    int n = b >> 8, c0 = ((b >> 6) & 3) * 64, l0 = (b & 63) * 64;
    const float* xp = x + ((size_t)n * CH + c0) * LEN + l0;
    #pragma unroll
    for (int i = 0; i < 4; i++) {
        int idx = t + i * 256;
        int c = idx >> 4, l4 = idx & 15;
        float4 v = *(const float4*)(xp + (size_t)c * LEN + l4 * 4);
        T[c][l4 * 4 + 0] = v.x; T[c][l4 * 4 + 1] = v.y;
        T[c][l4 * 4 + 2] = v.z; T[c][l4 * 4 + 3] = v.w;
        P16[c][l4] = (v.x + v.y + v.z + v.w) * 0.25f
                   + fmaxf(fmaxf(v.x, v.y), fmaxf(v.z, v.w));
    }
    __syncthreads();
    unsigned short* op = xbf + ((size_t)n * LEN + l0) * CH + c0;
    #pragma unroll
    for (int i = 0; i < 4; i++) {
        int idx = t + i * 256;
        int l = idx >> 4, c4 = idx & 15;
        uint2 pk;
        pk.x = pack2bf(T[c4 * 4 + 0][l], T[c4 * 4 + 1][l]);
        pk.y = pack2bf(T[c4 * 4 + 2][l], T[c4 * 4 + 3][l]);
        *(uint2*)(op + (size_t)l * CH + c4 * 4) = pk;
    }
    int p0 = l0 >> 2;
    #pragma unroll
    for (int k = 0; k < 2; k++) {
        int p = (t >> 5) + k * 8;
        int c2 = (t & 31) * 2;
        unsigned pk = pack2bf(P16[c2][p], P16[c2 + 1][p]);
        *(unsigned*)(poolT + ((size_t)n * LPOOL + p0 + p) * CH + c0 + c2) = pk;
    }
}

// ---------------------------------------------------------------------------
// MFMA GEMM: D[i][j] = sum_k A[i][k] * B[j][k], K = 256 (bf16, K-contig rows).
// Epilogue: + biasRow[i]; *scale[i]+shift[i]; *outScale.
// Output modes (per 128-row tile):
//   outF != 0                : f32 [row][col] (ld NN), LDS-restaged 512B stores
//   rowTile <  rowSplit      : bf16 at out1 + col*cs1 + row  (column-major-ish)
//   rowTile >= rowSplit      : bf16 at out2 + (row-rowSplit)*rs2 + col
__global__ __launch_bounds__(256) void gemm_mfma(
    const unsigned short* __restrict__ A,
    const unsigned short* __restrict__ B, size_t bBatch,
    const float* __restrict__ biasRow,
    const float* __restrict__ scale, const float* __restrict__ shift,
    float* __restrict__ outF, size_t oFBatch,
    unsigned short* __restrict__ out1, size_t o1Batch, int cs1,
    unsigned short* __restrict__ out2, size_t o2Batch, int rs2, int rowSplit,
    int NN, float outScale)
{
    __shared__ unsigned short smem[2 * 128 * 72];  // As | Bs ; reused for epilogue
    unsigned short* As = smem;
    unsigned short* Bs = smem + 128 * 72;

    int n = blockIdx.z;
    int t = threadIdx.x;
    int wave = t >> 6, lane = t & 63, m = lane & 15, quad = lane >> 4;
    int wm = wave & 1, wn = wave >> 1;
    int rowTile = blockIdx.y * 128;
    int col0 = blockIdx.x * 128;

    const unsigned short* Ab = A + (size_t)rowTile * 256;
    const unsigned short* Bb = B + (size_t)n * bBatch + (size_t)col0 * 256;

    float4e acc[4][4] = {};

    for (int kk = 0; kk < 256; kk += 64) {
        #pragma unroll
        for (int i = 0; i < 4; i++) {
            int idx = t + i * 256;
            int row = idx >> 3, ch = idx & 7;
            *(uint4*)&As[row * 72 + ch * 8] = *(const uint4*)(Ab + (size_t)row * 256 + kk + ch * 8);
            *(uint4*)&Bs[row * 72 + ch * 8] = *(const uint4*)(Bb + (size_t)row * 256 + kk + ch * 8);
        }
        __syncthreads();
        #pragma unroll
        for (int kc = 0; kc < 2; kc++) {
            short8 af[4], bfr[4];
            #pragma unroll
            for (int i = 0; i < 4; i++)
                af[i] = *(const short8*)&As[(wm * 64 + i * 16 + m) * 72 + kc * 32 + quad * 8];
            #pragma unroll
            for (int j = 0; j < 4; j++)
                bfr[j] = *(const short8*)&Bs[(wn * 64 + j * 16 + m) * 72 + kc * 32 + quad * 8];
            #pragma unroll
            for (int i = 0; i < 4; i++)
                #pragma unroll
                for (int j = 0; j < 4; j++)
                    acc[i][j] = __builtin_amdgcn_mfma_f32_16x16x32_bf16(af[i], bfr[j], acc[i][j], 0, 0, 0);
        }
        __syncthreads();
    }

    if (outF) {
        // fp32 output, restaged through LDS in two 64-row halves
        float* TOf = (float*)smem;   // [64][128]
        float* dst = outF + (size_t)n * oFBatch;
        #pragma unroll
        for (int half = 0; half < 2; half++) {
            __syncthreads();
            if (wm == half) {
                #pragma unroll
                for (int i = 0; i < 4; i++) {
                    int rowL = i * 16 + quad * 4;
                    int rowG = rowTile + half * 64 + rowL;
                    float br[4], sc[4], sh[4];
                    #pragma unroll
                    for (int r = 0; r < 4; r++) {
                        br[r] = biasRow ? biasRow[rowG + r] : 0.0f;
                        sc[r] = scale ? scale[rowG + r] : 1.0f;
                        sh[r] = shift ? shift[rowG + r] : 0.0f;
                    }
                    #pragma unroll
                    for (int j = 0; j < 4; j++) {
                        int colL = wn * 64 + j * 16 + m;
                        float4e c = acc[i][j];
                        #pragma unroll
                        for (int r = 0; r < 4; r++)
                            TOf[(rowL + r) * 128 + colL] = ((c[r] + br[r]) * sc[r] + sh[r]) * outScale;
                    }
                }
            }
            __syncthreads();
            #pragma unroll
            for (int w = 0; w < 8; w++) {
                int idx = t + w * 256;
                int row = idx >> 5, c4 = idx & 31;
                *(float4*)(dst + (size_t)(rowTile + half * 64 + row) * NN + col0 + c4 * 4) =
                    *(const float4*)&TOf[row * 128 + c4 * 4];
            }
        }
        return;
    }

    bool mode2 = (rowTile >= rowSplit);
    unsigned short* TO = smem;
    #pragma unroll
    for (int i = 0; i < 4; i++) {
        int rowL = wm * 64 + i * 16 + quad * 4;
        int rowG = rowTile + rowL;
        float br[4], sc[4], sh[4];
        #pragma unroll
        for (int r = 0; r < 4; r++) {
            br[r] = biasRow ? biasRow[rowG + r] : 0.0f;
            sc[r] = scale ? scale[rowG + r] : 1.0f;
            sh[r] = shift ? shift[rowG + r] : 0.0f;
        }
        #pragma unroll
        for (int j = 0; j < 4; j++) {
            int colL = wn * 64 + j * 16 + m;
            float4e c = acc[i][j];
            float v0 = ((c[0] + br[0]) * sc[0] + sh[0]) * outScale;
            float v1 = ((c[1] + br[1]) * sc[1] + sh[1]) * outScale;
            float v2 = ((c[2] + br[2]) * sc[2] + sh[2]) * outScale;
            float v3 = ((c[3] + br[3]) * sc[3] + sh[3]) * outScale;
            if (!mode2) {
                uint2 pk;
                pk.x = pack2bf(v0, v1);
                pk.y = pack2bf(v2, v3);
                *(uint2*)&TO[colL * 136 + rowL] = pk;
            } else {
                TO[(rowL + 0) * 136 + colL] = f2bf(v0);
                TO[(rowL + 1) * 136 + colL] = f2bf(v1);
                TO[(rowL + 2) * 136 + colL] = f2bf(v2);
                TO[(rowL + 3) * 136 + colL] = f2bf(v3);
            }
        }
    }
    __syncthreads();
    if (!mode2) {
        unsigned short* dst = out1 + (size_t)n * o1Batch;
        #pragma unroll
        for (int w = 0; w < 8; w++) {
            int idx = t + w * 256;
            int l = idx >> 4, ch = idx & 15;
            *(uint4*)(dst + (size_t)(col0 + l) * cs1 + rowTile + ch * 8) =
                *(const uint4*)&TO[l * 136 + ch * 8];
        }
    } else {
        unsigned short* dst = out2 + (size_t)n * o2Batch;
        int rowBase = rowTile - rowSplit;
        #pragma unroll
        for (int w = 0; w < 8; w++) {
            int idx = t + w * 256;
            int row = idx >> 4, ch = idx & 15;
            *(uint4*)(dst + (size_t)(rowBase + row) * rs2 + col0 + ch * 8) =
                *(const uint4*)&TO[row * 136 + ch * 8];
        }
    }
}

// ---------------------------------------------------------------------------
// MFMA flash attention, 32x32x16, latency-focused restructure.
// vs round 3 (which proved latency-bound: MfmaUtil 13%, VALUBusy 20%, both
// pipes idle 2/3 of the time at 2 waves/SIMD):
//  (a) 2-way KV-split: block = 64 q, 4 waves; wave (qc=w&1, ks=w>>1) handles
//      32 q x 512 keys. Fixed-shift softmax (no per-wave max) makes partials
//      additive: O = O0+O1, l = l0+l1, combined once via a small LDS buffer.
//      Grid 1024 blocks -> 16 waves/CU = 4/SIMD (2x TLP).
//  (b) No LDS staging: K/V fragments are loaded straight from global with
//      MFMA-native 16B/lane patterns (per-(n,h) K/V = 256 KB, L2-resident,
//      reused by 64 blocks). Removes all main-loop barriers and the 2.1M
//      LDS bank conflicts; waves run fully independent.
// Frag patterns (verified by the round-2/3 passing kernel, just re-aimed at
// global): QK A-frag lane l: K[k0+(l&31)][dc*16+(l>>5)*8+..7];
// V A-frag lane l: V^T[eh*32+(l&31)][k0+kc2*16+(l>>5)*8+..7].
// Qb: [N,L,C] bf16 (pre-scaled log2(e)/8); Kb: [N,L2,C]; Vb: [N,C,L2];
// Obf: [N,L,C] bf16.
__global__ __launch_bounds__(256, 4) void attn_mfma(
    const unsigned short* __restrict__ Qb,
    const unsigned short* __restrict__ Kb,
    const unsigned short* __restrict__ Vb,
    unsigned short* __restrict__ Obf)
{
    __shared__ float comb[2 * 64 * 33];   // upper-wave partials: 32 O + 1 l

    int qb = blockIdx.x;          // 64-row q block
    int h  = blockIdx.y;
    int n  = blockIdx.z;
    int t  = threadIdx.x;
    int wave = t >> 6, lane = t & 63;
    int col = lane & 31;          // q within wave
    int hi  = lane >> 5;
    int qc = wave & 1;            // q chunk within block
    int ks = wave >> 1;           // key half (0: keys 0..511, 1: 512..1023)
    int l0 = qb * 64 + qc * 32;
    int kbase = ks * 512;

    // Q B-frags: lane holds q=col, dims dc*16 + hi*8 .. +7
    const unsigned short* qp = Qb + ((size_t)n * LEN + l0 + col) * CH + h * HD + hi * 8;
    short8 bQ[4];
    #pragma unroll
    for (int dc = 0; dc < 4; dc++)
        bQ[dc] = *(const short8*)(qp + dc * 16);

    float16e Oa[2];
    #pragma unroll
    for (int e = 0; e < 2; e++)
        #pragma unroll
        for (int r = 0; r < 16; r++) Oa[e][r] = 0.0f;
    float l_run = 0.0f;

    const float NEG = -17.312340f;   // -12 * log2(e)

    // per-lane global fragment pointers (advance by 32 keys per tile)
    const unsigned short* kPtr =
        Kb + ((size_t)n * LPOOL + kbase + col) * CH + h * HD + hi * 8;
    const unsigned short* vPtr0 =
        Vb + ((size_t)n * CH + h * HD + col) * LPOOL + kbase + hi * 8;
    const unsigned short* vPtr1 = vPtr0 + (size_t)32 * LPOOL;

    #pragma unroll 2
    for (int kt = 0; kt < 16; kt++) {
        // fragment loads for this 32-key tile (independent; no barriers, so
        // the scheduler overlaps them with the previous iteration's compute)
        short8 kf0 = *(const short8*)(kPtr);
        short8 kf1 = *(const short8*)(kPtr + 16);
        short8 kf2 = *(const short8*)(kPtr + 32);
        short8 kf3 = *(const short8*)(kPtr + 48);
        short8 av00 = *(const short8*)(vPtr0);
        short8 av01 = *(const short8*)(vPtr0 + 16);
        short8 av10 = *(const short8*)(vPtr1);
        short8 av11 = *(const short8*)(vPtr1 + 16);
        kPtr  += 32 * CH;
        vPtr0 += 32;
        vPtr1 += 32;

        // QK^T for 32 keys x 32 q
        float16e c;
        #pragma unroll
        for (int r = 0; r < 16; r++) c[r] = NEG;
        __builtin_amdgcn_s_setprio(1);
        c = __builtin_amdgcn_mfma_f32_32x32x16_bf16(kf0, bQ[0], c, 0, 0, 0);
        c = __builtin_amdgcn_mfma_f32_32x32x16_bf16(kf1, bQ[1], c, 0, 0, 0);
        c = __builtin_amdgcn_mfma_f32_32x32x16_bf16(kf2, bQ[2], c, 0, 0, 0);
        c = __builtin_amdgcn_mfma_f32_32x32x16_bf16(kf3, bQ[3], c, 0, 0, 0);
        __builtin_amdgcn_s_setprio(0);

        float p[16];
        #pragma unroll
        for (int r = 0; r < 16; r++) p[r] = fast_exp2(c[r]);
        l_run += ((p[0] + p[1]) + (p[2] + p[3])) + ((p[4] + p[5]) + (p[6] + p[7]))
               + ((p[8] + p[9]) + (p[10] + p[11])) + ((p[12] + p[13]) + (p[14] + p[15]));

        // P -> bf16 B-frags (keys kc2*16..+15 of this tile)
        union { unsigned u[4]; short8 s; } bP[2];
        #pragma unroll
        for (int kc2 = 0; kc2 < 2; kc2++) {
            int rb = kc2 * 8;
            unsigned A0 = pack2bf(p[rb + 0], p[rb + 1]);
            unsigned B0 = pack2bf(p[rb + 4], p[rb + 5]);
            unsigned A1 = pack2bf(p[rb + 2], p[rb + 3]);
            unsigned B1 = pack2bf(p[rb + 6], p[rb + 7]);
            uint2v s0 = __builtin_amdgcn_permlane32_swap(A0, B0, false, false);
            uint2v s1 = __builtin_amdgcn_permlane32_swap(A1, B1, false, false);
            bP[kc2].u[0] = s0[0];
            bP[kc2].u[1] = s1[0];
            bP[kc2].u[2] = s0[1];
            bP[kc2].u[3] = s1[1];
        }

        // PV: O[eh] += V^T-frag x P-frag
        __builtin_amdgcn_s_setprio(1);
        Oa[0] = __builtin_amdgcn_mfma_f32_32x32x16_bf16(av00, bP[0].s, Oa[0], 0, 0, 0);
        Oa[0] = __builtin_amdgcn_mfma_f32_32x32x16_bf16(av01, bP[1].s, Oa[0], 0, 0, 0);
        Oa[1] = __builtin_amdgcn_mfma_f32_32x32x16_bf16(av10, bP[0].s, Oa[1], 0, 0, 0);
        Oa[1] = __builtin_amdgcn_mfma_f32_32x32x16_bf16(av11, bP[1].s, Oa[1], 0, 0, 0);
        __builtin_amdgcn_s_setprio(0);
    }

    // combine key-half partials: waves 2,3 hand off to waves 0,1
    if (wave >= 2) {
        float* cb = &comb[((wave - 2) * 64 + lane) * 33];
        #pragma unroll
        for (int eh = 0; eh < 2; eh++)
            #pragma unroll
            for (int r = 0; r < 16; r++)
                cb[eh * 16 + r] = Oa[eh][r];
        cb[32] = l_run;
    }
    __syncthreads();
    if (wave < 2) {
        const float* cb = &comb[(wave * 64 + lane) * 33];
        #pragma unroll
        for (int eh = 0; eh < 2; eh++)
            #pragma unroll
            for (int r = 0; r < 16; r++)
                Oa[eh][r] += cb[eh * 16 + r];
        l_run += cb[32];

        // normalize + store: e = (r&3) + 8*(r>>2) + 4*hi + 32*eh
        float l = l_run + __shfl_xor(l_run, 32);
        float inv = 1.0f / l;
        unsigned short* op = Obf + ((size_t)n * LEN + l0 + col) * CH + h * HD + hi * 4;
        #pragma unroll
        for (int eh = 0; eh < 2; eh++)
            #pragma unroll
            for (int rq = 0; rq < 4; rq++) {
                int r = rq * 4;
                uint2 pk;
                pk.x = pack2bf(Oa[eh][r + 0] * inv, Oa[eh][r + 1] * inv);
                pk.y = pack2bf(Oa[eh][r + 2] * inv, Oa[eh][r + 3] * inv);
                *(uint2*)(op + eh * 32 + rq * 8) = pk;
            }
    }
}

// ---------------------------------------------------------------------------
extern "C" void kernel_launch(void* const* d_in, const int* in_sizes, int n_in,
                              void* d_out, int out_size, void* d_ws, size_t ws_size,
                              hipStream_t stream)
{
    const float* x  = (const float*)d_in[0];
    const float* Wq = (const float*)d_in[1];
    const float* bq = (const float*)d_in[2];
    const float* Wk = (const float*)d_in[3];
    const float* bk = (const float*)d_in[4];
    const float* Wv = (const float*)d_in[5];
    const float* bv = (const float*)d_in[6];
    const float* Wo = (const float*)d_in[7];
    const float* bo = (const float*)d_in[8];
    const float* Wa = (const float*)d_in[9];
    const float* g1 = (const float*)d_in[10];
    const float* b1 = (const float*)d_in[11];
    const float* m1 = (const float*)d_in[12];
    const float* v1 = (const float*)d_in[13];
    const float* g2 = (const float*)d_in[14];
    const float* b2 = (const float*)d_in[15];
    const float* m2 = (const float*)d_in[16];
    const float* v2 = (const float*)d_in[17];

    float* wsf      = (float*)d_ws;
    float* bn_scale = wsf;            // 256
    float* bn_shift = wsf + 256;      // 256
    float* bkv      = wsf + 512;      // 512
    unsigned short* Wbf   = (unsigned short*)(wsf + 1024);          // 5*65536
    unsigned short* xbf   = Wbf + 5 * 65536;                        // [N,L,C]
    unsigned short* poolT = xbf   + (size_t)NBATCH * LEN * CH;      // [N,L2,C]
    unsigned short* xabf  = poolT + (size_t)NBATCH * LPOOL * CH;    // [N,L2,C]
    unsigned short* Kbf   = xabf  + (size_t)NBATCH * LPOOL * CH;    // [N,L2,C]
    unsigned short* Vbf   = Kbf   + (size_t)NBATCH * LPOOL * CH;    // [N,C,L2]
    unsigned short* Qbf   = Vbf   + (size_t)NBATCH * LPOOL * CH;    // [N,L,C]
    unsigned short* Obf   = Qbf   + (size_t)NBATCH * LEN * CH;      // [N,L,C]

    // 1. transpose+pool over x, weights->bf16, BN affine, bkv concat
    transpool_setup<<<1345, 256, 0, stream>>>(x, xbf, poolT,
        Wq, Wk, Wv, Wo, Wa, Wbf,
        g1, b1, m1, v1, g2, b2, m2, v2, bn_scale, bn_shift, bk, bv, bkv);

    // 2. q = Wq @ x + bq, pre-scaled by log2(e)/8 -> Qbf [N,L,C]
    gemm_mfma<<<dim3(32, 2, 4), 256, 0, stream>>>(
        Wbf + 0 * 65536, xbf, (size_t)LEN * CH, bq, nullptr, nullptr,
        nullptr, 0, Qbf, (size_t)LEN * CH, 256, nullptr, 0, 0, 1 << 30,
        LEN, 0.18033688f);

    // 3. xa = BN2(BN1(Wa @ pool(x))) -> xabf [N,L2,C]
    gemm_mfma<<<dim3(8, 2, 4), 256, 0, stream>>>(
        Wbf + 4 * 65536, poolT, (size_t)LPOOL * CH, nullptr, bn_scale, bn_shift,
        nullptr, 0, xabf, (size_t)LPOOL * CH, 256, nullptr, 0, 0, 1 << 30,
        LPOOL, 1.0f);

    // 4. fused k+v: A = [Wk;Wv] (contiguous in Wbf), M=512.
    //    rows 0..255 -> Kbf [l2][c] (mode1); rows 256..511 -> Vbf [c][l2] (mode2)
    gemm_mfma<<<dim3(8, 4, 4), 256, 0, stream>>>(
        Wbf + 1 * 65536, xabf, (size_t)LPOOL * CH, bkv, nullptr, nullptr,
        nullptr, 0, Kbf, (size_t)LPOOL * CH, 256, Vbf, (size_t)LPOOL * CH, LPOOL, 256,
        LPOOL, 1.0f);

    // 5. attention -> Obf [N,L,C] bf16
    //    (64-q blocks, 32 q/wave, 2-way KV-split, L2-direct fragments)
    attn_mfma<<<dim3(LEN / 64, NH, NBATCH), 256, 0, stream>>>(Qbf, Kbf, Vbf, Obf);

    // 6. out = Wo @ o + bo -> f32 d_out [N,C,L]
    gemm_mfma<<<dim3(32, 2, 4), 256, 0, stream>>>(
        Wbf + 3 * 65536, Obf, (size_t)LEN * CH, bo, nullptr, nullptr,
        (float*)d_out, (size_t)CH * LEN, nullptr, 0, 0, nullptr, 0, 0, 1 << 30,
        LEN, 1.0f);
}

// Round 5
// 168.847 us; speedup vs baseline: 1.1939x; 1.1939x over previous
//
#include <hip/hip_runtime.h>
#include <stdint.h>

// Problem constants
constexpr int NBATCH = 4;
constexpr int CH     = 256;   // channels
constexpr int LEN    = 4096;  // sequence length
constexpr int LPOOL  = 1024;  // pooled length (LEN/4)
constexpr int NH     = 4;     // heads
constexpr int HD     = 64;    // head dim

typedef __attribute__((ext_vector_type(8))) short short8;     // 8 bf16 in 4 VGPRs
typedef __attribute__((ext_vector_type(4))) float float4e;    // MFMA C/D 16x16
typedef __attribute__((ext_vector_type(16))) float float16e;  // MFMA C/D 32x32
typedef __attribute__((ext_vector_type(2))) unsigned uint2v;

__device__ __forceinline__ unsigned short f2bf(float f) {
    union { unsigned int i; float f; } v; v.f = f;
    unsigned int lsb = (v.i >> 16) & 1u;
    v.i += 0x7fffu + lsb;
    return (unsigned short)(v.i >> 16);
}
// pack two floats -> two bf16 (round-half-up via +0x8000, then byte-perm)
__device__ __forceinline__ unsigned pack2bf(float lo, float hi) {
    unsigned a = __float_as_uint(lo) + 0x8000u;
    unsigned b = __float_as_uint(hi) + 0x8000u;
    return __builtin_amdgcn_perm(b, a, 0x07060302u);
}
// single-instruction 2^x (OCML exp2f without fast-math is ~12 VALU ops)
__device__ __forceinline__ float fast_exp2(float x) {
#if __has_builtin(__builtin_amdgcn_exp2f)
    return __builtin_amdgcn_exp2f(x);
#else
    float r;
    asm("v_exp_f32 %0, %1" : "=v"(r) : "v"(x));
    return r;
#endif
}
// async global->LDS DMA, 16B per lane; LDS dest = wave-uniform base + lane*16
__device__ __forceinline__ void gload16(const void* g, void* l) {
    __builtin_amdgcn_global_load_lds(
        (const __attribute__((address_space(1))) unsigned int*)g,
        (__attribute__((address_space(3))) unsigned int*)l, 16, 0, 0);
}

// ---------------------------------------------------------------------------
// Fused: blocks 0..1023 do transpose+pool over x; blocks 1024..1343 cast the
// 5 weight matrices to bf16; block 1344 computes BN affine + bkv concat.
__global__ __launch_bounds__(256) void transpool_setup(
    const float* __restrict__ x, unsigned short* __restrict__ xbf,
    unsigned short* __restrict__ poolT,
    const float* __restrict__ w0, const float* __restrict__ w1,
    const float* __restrict__ w2, const float* __restrict__ w3,
    const float* __restrict__ w4, unsigned short* __restrict__ outW,
    const float* __restrict__ g1, const float* __restrict__ b1,
    const float* __restrict__ m1, const float* __restrict__ v1,
    const float* __restrict__ g2, const float* __restrict__ b2,
    const float* __restrict__ m2, const float* __restrict__ v2,
    float* __restrict__ scale, float* __restrict__ shift,
    const float* __restrict__ bk, const float* __restrict__ bv,
    float* __restrict__ bkv)
{
    __shared__ float T[64][65];
    __shared__ float P16[64][17];
    int b = blockIdx.x, t = threadIdx.x;
    if (b >= 1024) {
        int sb = b - 1024;
        if (sb < 320) {
            int gid = sb * 256 + t;
            int w = gid >> 14;
            int off = (gid & 16383) * 4;
            const float* src = (w == 0) ? w0 : (w == 1) ? w1 : (w == 2) ? w2 : (w == 3) ? w3 : w4;
            float4 v = *(const float4*)(src + off);
            uint2 pk;
            pk.x = pack2bf(v.x, v.y);
            pk.y = pack2bf(v.z, v.w);
            *(uint2*)(outW + w * 65536 + off) = pk;
        } else {
            float inv1 = g1[t] * rsqrtf(v1[t] + 1e-5f);
            float inv2 = g2[t] * rsqrtf(v2[t] + 1e-5f);
            scale[t] = inv1 * inv2;
            shift[t] = (b1[t] - m1[t] * inv1) * inv2 + (b2[t] - m2[t] * inv2);
            bkv[t] = bk[t];
            bkv[256 + t] = bv[t];
        }
        return;
    }
    int n = b >> 8, c0 = ((b >> 6) & 3) * 64, l0 = (b & 63) * 64;
    const float* xp = x + ((size_t)n * CH + c0) * LEN + l0;
    #pragma unroll
    for (int i = 0; i < 4; i++) {
        int idx = t + i * 256;
        int c = idx >> 4, l4 = idx & 15;
        float4 v = *(const float4*)(xp + (size_t)c * LEN + l4 * 4);
        T[c][l4 * 4 + 0] = v.x; T[c][l4 * 4 + 1] = v.y;
        T[c][l4 * 4 + 2] = v.z; T[c][l4 * 4 + 3] = v.w;
        P16[c][l4] = (v.x + v.y + v.z + v.w) * 0.25f
                   + fmaxf(fmaxf(v.x, v.y), fmaxf(v.z, v.w));
    }
    __syncthreads();
    unsigned short* op = xbf + ((size_t)n * LEN + l0) * CH + c0;
    #pragma unroll
    for (int i = 0; i < 4; i++) {
        int idx = t + i * 256;
        int l = idx >> 4, c4 = idx & 15;
        uint2 pk;
        pk.x = pack2bf(T[c4 * 4 + 0][l], T[c4 * 4 + 1][l]);
        pk.y = pack2bf(T[c4 * 4 + 2][l], T[c4 * 4 + 3][l]);
        *(uint2*)(op + (size_t)l * CH + c4 * 4) = pk;
    }
    int p0 = l0 >> 2;
    #pragma unroll
    for (int k = 0; k < 2; k++) {
        int p = (t >> 5) + k * 8;
        int c2 = (t & 31) * 2;
        unsigned pk = pack2bf(P16[c2][p], P16[c2 + 1][p]);
        *(unsigned*)(poolT + ((size_t)n * LPOOL + p0 + p) * CH + c0 + c2) = pk;
    }
}

// ---------------------------------------------------------------------------
// MFMA GEMM: D[i][j] = sum_k A[i][k] * B[j][k], K = 256 (bf16, K-contig rows).
// Epilogue: + biasRow[i]; *scale[i]+shift[i]; *outScale.
// Output modes (per 128-row tile):
//   outF != 0                : f32 [row][col] (ld NN), LDS-restaged 512B stores
//   rowTile <  rowSplit      : bf16 at out1 + col*cs1 + row  (column-major-ish)
//   rowTile >= rowSplit      : bf16 at out2 + (row-rowSplit)*rs2 + col
__global__ __launch_bounds__(256) void gemm_mfma(
    const unsigned short* __restrict__ A,
    const unsigned short* __restrict__ B, size_t bBatch,
    const float* __restrict__ biasRow,
    const float* __restrict__ scale, const float* __restrict__ shift,
    float* __restrict__ outF, size_t oFBatch,
    unsigned short* __restrict__ out1, size_t o1Batch, int cs1,
    unsigned short* __restrict__ out2, size_t o2Batch, int rs2, int rowSplit,
    int NN, float outScale)
{
    __shared__ unsigned short smem[2 * 128 * 72];  // As | Bs ; reused for epilogue
    unsigned short* As = smem;
    unsigned short* Bs = smem + 128 * 72;

    int n = blockIdx.z;
    int t = threadIdx.x;
    int wave = t >> 6, lane = t & 63, m = lane & 15, quad = lane >> 4;
    int wm = wave & 1, wn = wave >> 1;
    int rowTile = blockIdx.y * 128;
    int col0 = blockIdx.x * 128;

    const unsigned short* Ab = A + (size_t)rowTile * 256;
    const unsigned short* Bb = B + (size_t)n * bBatch + (size_t)col0 * 256;

    float4e acc[4][4] = {};

    for (int kk = 0; kk < 256; kk += 64) {
        #pragma unroll
        for (int i = 0; i < 4; i++) {
            int idx = t + i * 256;
            int row = idx >> 3, ch = idx & 7;
            *(uint4*)&As[row * 72 + ch * 8] = *(const uint4*)(Ab + (size_t)row * 256 + kk + ch * 8);
            *(uint4*)&Bs[row * 72 + ch * 8] = *(const uint4*)(Bb + (size_t)row * 256 + kk + ch * 8);
        }
        __syncthreads();
        #pragma unroll
        for (int kc = 0; kc < 2; kc++) {
            short8 af[4], bfr[4];
            #pragma unroll
            for (int i = 0; i < 4; i++)
                af[i] = *(const short8*)&As[(wm * 64 + i * 16 + m) * 72 + kc * 32 + quad * 8];
            #pragma unroll
            for (int j = 0; j < 4; j++)
                bfr[j] = *(const short8*)&Bs[(wn * 64 + j * 16 + m) * 72 + kc * 32 + quad * 8];
            #pragma unroll
            for (int i = 0; i < 4; i++)
                #pragma unroll
                for (int j = 0; j < 4; j++)
                    acc[i][j] = __builtin_amdgcn_mfma_f32_16x16x32_bf16(af[i], bfr[j], acc[i][j], 0, 0, 0);
        }
        __syncthreads();
    }

    if (outF) {
        // fp32 output, restaged through LDS in two 64-row halves
        float* TOf = (float*)smem;   // [64][128]
        float* dst = outF + (size_t)n * oFBatch;
        #pragma unroll
        for (int half = 0; half < 2; half++) {
            __syncthreads();
            if (wm == half) {
                #pragma unroll
                for (int i = 0; i < 4; i++) {
                    int rowL = i * 16 + quad * 4;
                    int rowG = rowTile + half * 64 + rowL;
                    float br[4], sc[4], sh[4];
                    #pragma unroll
                    for (int r = 0; r < 4; r++) {
                        br[r] = biasRow ? biasRow[rowG + r] : 0.0f;
                        sc[r] = scale ? scale[rowG + r] : 1.0f;
                        sh[r] = shift ? shift[rowG + r] : 0.0f;
                    }
                    #pragma unroll
                    for (int j = 0; j < 4; j++) {
                        int colL = wn * 64 + j * 16 + m;
                        float4e c = acc[i][j];
                        #pragma unroll
                        for (int r = 0; r < 4; r++)
                            TOf[(rowL + r) * 128 + colL] = ((c[r] + br[r]) * sc[r] + sh[r]) * outScale;
                    }
                }
            }
            __syncthreads();
            #pragma unroll
            for (int w = 0; w < 8; w++) {
                int idx = t + w * 256;
                int row = idx >> 5, c4 = idx & 31;
                *(float4*)(dst + (size_t)(rowTile + half * 64 + row) * NN + col0 + c4 * 4) =
                    *(const float4*)&TOf[row * 128 + c4 * 4];
            }
        }
        return;
    }

    bool mode2 = (rowTile >= rowSplit);
    unsigned short* TO = smem;
    #pragma unroll
    for (int i = 0; i < 4; i++) {
        int rowL = wm * 64 + i * 16 + quad * 4;
        int rowG = rowTile + rowL;
        float br[4], sc[4], sh[4];
        #pragma unroll
        for (int r = 0; r < 4; r++) {
            br[r] = biasRow ? biasRow[rowG + r] : 0.0f;
            sc[r] = scale ? scale[rowG + r] : 1.0f;
            sh[r] = shift ? shift[rowG + r] : 0.0f;
        }
        #pragma unroll
        for (int j = 0; j < 4; j++) {
            int colL = wn * 64 + j * 16 + m;
            float4e c = acc[i][j];
            float v0 = ((c[0] + br[0]) * sc[0] + sh[0]) * outScale;
            float v1 = ((c[1] + br[1]) * sc[1] + sh[1]) * outScale;
            float v2 = ((c[2] + br[2]) * sc[2] + sh[2]) * outScale;
            float v3 = ((c[3] + br[3]) * sc[3] + sh[3]) * outScale;
            if (!mode2) {
                uint2 pk;
                pk.x = pack2bf(v0, v1);
                pk.y = pack2bf(v2, v3);
                *(uint2*)&TO[colL * 136 + rowL] = pk;
            } else {
                TO[(rowL + 0) * 136 + colL] = f2bf(v0);
                TO[(rowL + 1) * 136 + colL] = f2bf(v1);
                TO[(rowL + 2) * 136 + colL] = f2bf(v2);
                TO[(rowL + 3) * 136 + colL] = f2bf(v3);
            }
        }
    }
    __syncthreads();
    if (!mode2) {
        unsigned short* dst = out1 + (size_t)n * o1Batch;
        #pragma unroll
        for (int w = 0; w < 8; w++) {
            int idx = t + w * 256;
            int l = idx >> 4, ch = idx & 15;
            *(uint4*)(dst + (size_t)(col0 + l) * cs1 + rowTile + ch * 8) =
                *(const uint4*)&TO[l * 136 + ch * 8];
        }
    } else {
        unsigned short* dst = out2 + (size_t)n * o2Batch;
        int rowBase = rowTile - rowSplit;
        #pragma unroll
        for (int w = 0; w < 8; w++) {
            int idx = t + w * 256;
            int row = idx >> 4, ch = idx & 15;
            *(uint4*)(dst + (size_t)(rowBase + row) * rs2 + col0 + ch * 8) =
                *(const uint4*)&TO[row * 136 + ch * 8];
        }
    }
}

// ---------------------------------------------------------------------------
// MFMA flash attention, 32x32x16, async-DMA pipelined (T3/T4).
// The r0-r3 loop was the measured "2-phase" pathology: reg-prefetch ->
// vmcnt(0) drain -> ds_write -> __syncthreads (which emits a FULL
// vmcnt(0)+lgkmcnt(0) drain) per tile: ~72% overhead regardless of compute
// shape -- which is why 4 structural variants all landed at 45-68 us.
// This version: K/V tiles staged by __builtin_amdgcn_global_load_lds (async
// DMA, no register round-trip), raw s_barrier (no compiler drain), explicit
// s_waitcnt vmcnt(0) placed BEFORE the barrier so tile t's DMA -- issued one
// tile earlier -- has tile t-1's whole compute to land. Per iteration:
//   vmcnt(0) ; s_barrier ; issue DMA(t+1 -> other buf) ; compute(t)
// LDS swizzle is preserved by pre-swizzling the GLOBAL source chunk
// (ch ^= row&7) while the DMA dest stays linear (rule: linear dest +
// inverse-swizzled source + swizzled read); coalescing unchanged (the
// permutation stays inside each 128B row segment).
// Compute per wave unchanged from r3: 32 q x 64 keys/tile, QK^T via
// mfma_32x32x16 (D[key][q]), fixed-shift softmax, P repacked with
// pack2bf + permlane32_swap, PV accumulates 64-dim output.
__global__ __launch_bounds__(256, 2) void attn_mfma(
    const unsigned short* __restrict__ Qb,
    const unsigned short* __restrict__ Kb,
    const unsigned short* __restrict__ Vb,
    unsigned short* __restrict__ Obf)
{
    __shared__ unsigned short Ks[2][64 * 64];   // [key][dim], swizzled content
    __shared__ unsigned short Vs[2][64 * 64];   // [e][key],  swizzled content

    int qb = blockIdx.x;          // 128-row q block
    int h  = blockIdx.y;
    int n  = blockIdx.z;
    int t  = threadIdx.x;
    int wave = t >> 6, lane = t & 63;
    int col = lane & 31;          // q within wave
    int hi  = lane >> 5;
    int l0 = qb * 128 + wave * 32;

    // Q B-frags: lane holds q=col, dims dc*16 + hi*8 .. +7
    const unsigned short* qp = Qb + ((size_t)n * LEN + l0 + col) * CH + h * HD + hi * 8;
    short8 bQ[4];
    #pragma unroll
    for (int dc = 0; dc < 4; dc++)
        bQ[dc] = *(const short8*)(qp + dc * 16);

    float16e Oa[2];
    #pragma unroll
    for (int e = 0; e < 2; e++)
        #pragma unroll
        for (int r = 0; r < 16; r++) Oa[e][r] = 0.0f;
    float l_run = 0.0f;

    const unsigned short* KgBase = Kb + (size_t)n * LPOOL * CH + h * HD;
    const unsigned short* VgBase = Vb + ((size_t)n * CH + h * HD) * LPOOL;
    const float NEG = -17.312340f;   // -12 * log2(e)

    // staging geometry: chunk idx = t + i*256 (i=0,1); row = idx>>3, ch = idx&7.
    // DMA writes LDS linearly at idx*16 bytes; source chunk = ch ^ (row&7)
    // so LDS[row*128 + b] holds global byte b ^ ((row&7)<<4)  (involution).
    int srow[2], schs[2], ldsb[2];
    #pragma unroll
    for (int i = 0; i < 2; i++) {
        int idx = t + i * 256;
        srow[i] = idx >> 3;
        schs[i] = (idx & 7) ^ (srow[i] & 7);
        ldsb[i] = wave * 1024 + i * 4096;   // wave-uniform DMA base (bytes)
    }
    // swizzled read offsets: group g (32-row half), chunk c (16B within row)
    int ldoff[2][4];
    #pragma unroll
    for (int g = 0; g < 2; g++)
        #pragma unroll
        for (int c = 0; c < 4; c++) {
            int row = g * 32 + col;
            ldoff[g][c] = row * 128 + ((c * 32 + hi * 16) ^ ((row & 7) << 4));
        }

    // prologue: DMA tile 0 -> buf 0
    #pragma unroll
    for (int i = 0; i < 2; i++) {
        gload16(KgBase + (size_t)srow[i] * CH + schs[i] * 8, (char*)Ks[0] + ldsb[i]);
        gload16(VgBase + (size_t)srow[i] * LPOOL + schs[i] * 8, (char*)Vs[0] + ldsb[i]);
    }

    #pragma unroll 2
    for (int kt = 0; kt < 16; kt++) {
        int cur = kt & 1;
        // my tile-kt DMA complete; barrier => everyone's complete AND everyone
        // finished reading buf[cur^1] (they read it during tile kt-1)
        asm volatile("s_waitcnt vmcnt(0)" ::: "memory");
        __builtin_amdgcn_sched_barrier(0);
        __builtin_amdgcn_s_barrier();
        __builtin_amdgcn_sched_barrier(0);
        // issue tile kt+1 DMA into the other buffer; flies under compute(kt)
        if (kt < 15) {
            int nxt = cur ^ 1;
            const unsigned short* ksrc = KgBase + (size_t)(kt + 1) * 64 * CH;
            const unsigned short* vsrc = VgBase + (kt + 1) * 64;
            #pragma unroll
            for (int i = 0; i < 2; i++) {
                gload16(ksrc + (size_t)srow[i] * CH + schs[i] * 8, (char*)Ks[nxt] + ldsb[i]);
                gload16(vsrc + (size_t)srow[i] * LPOOL + schs[i] * 8, (char*)Vs[nxt] + ldsb[i]);
            }
        }

        const char* KsC = (const char*)Ks[cur];
        const char* VsC = (const char*)Vs[cur];
        #pragma unroll
        for (int kh = 0; kh < 2; kh++) {
            // QK^T for 32-key half kh
            float16e c;
            #pragma unroll
            for (int r = 0; r < 16; r++) c[r] = NEG;
            __builtin_amdgcn_s_setprio(1);
            #pragma unroll
            for (int dc = 0; dc < 4; dc++) {
                short8 a = *(const short8*)(KsC + ldoff[kh][dc]);
                c = __builtin_amdgcn_mfma_f32_32x32x16_bf16(a, bQ[dc], c, 0, 0, 0);
            }
            __builtin_amdgcn_s_setprio(0);
            float p[16];
            #pragma unroll
            for (int r = 0; r < 16; r++) p[r] = fast_exp2(c[r]);
            l_run += ((p[0] + p[1]) + (p[2] + p[3])) + ((p[4] + p[5]) + (p[6] + p[7]))
                   + ((p[8] + p[9]) + (p[10] + p[11])) + ((p[12] + p[13]) + (p[14] + p[15]));
            // build P B-frags: chunk kc2 covers keys kh*32 + kc2*16 .. +15
            union { unsigned u[4]; short8 s; } bP[2];
            #pragma unroll
            for (int kc2 = 0; kc2 < 2; kc2++) {
                int rb = kc2 * 8;
                unsigned A0 = pack2bf(p[rb + 0], p[rb + 1]);
                unsigned B0 = pack2bf(p[rb + 4], p[rb + 5]);
                unsigned A1 = pack2bf(p[rb + 2], p[rb + 3]);
                unsigned B1 = pack2bf(p[rb + 6], p[rb + 7]);
                uint2v s0 = __builtin_amdgcn_permlane32_swap(A0, B0, false, false);
                uint2v s1 = __builtin_amdgcn_permlane32_swap(A1, B1, false, false);
                bP[kc2].u[0] = s0[0];
                bP[kc2].u[1] = s1[0];
                bP[kc2].u[2] = s0[1];
                bP[kc2].u[3] = s1[1];
            }
            // PV: O[eh] += V^T-frag x P-frag over this half's 2 k-chunks
            __builtin_amdgcn_s_setprio(1);
            #pragma unroll
            for (int eh = 0; eh < 2; eh++)
                #pragma unroll
                for (int kc2 = 0; kc2 < 2; kc2++) {
                    short8 av = *(const short8*)(VsC + ldoff[eh][kh * 2 + kc2]);
                    Oa[eh] = __builtin_amdgcn_mfma_f32_32x32x16_bf16(av, bP[kc2].s, Oa[eh], 0, 0, 0);
                }
            __builtin_amdgcn_s_setprio(0);
        }
    }

    // normalize + store: e = (r&3) + 8*(r>>2) + 4*hi + 32*eh
    float l = l_run + __shfl_xor(l_run, 32);
    float inv = 1.0f / l;
    unsigned short* op = Obf + ((size_t)n * LEN + l0 + col) * CH + h * HD + hi * 4;
    #pragma unroll
    for (int eh = 0; eh < 2; eh++)
        #pragma unroll
        for (int rq = 0; rq < 4; rq++) {
            int r = rq * 4;
            uint2 pk;
            pk.x = pack2bf(Oa[eh][r + 0] * inv, Oa[eh][r + 1] * inv);
            pk.y = pack2bf(Oa[eh][r + 2] * inv, Oa[eh][r + 3] * inv);
            *(uint2*)(op + eh * 32 + rq * 8) = pk;
        }
}

// ---------------------------------------------------------------------------
extern "C" void kernel_launch(void* const* d_in, const int* in_sizes, int n_in,
                              void* d_out, int out_size, void* d_ws, size_t ws_size,
                              hipStream_t stream)
{
    const float* x  = (const float*)d_in[0];
    const float* Wq = (const float*)d_in[1];
    const float* bq = (const float*)d_in[2];
    const float* Wk = (const float*)d_in[3];
    const float* bk = (const float*)d_in[4];
    const float* Wv = (const float*)d_in[5];
    const float* bv = (const float*)d_in[6];
    const float* Wo = (const float*)d_in[7];
    const float* bo = (const float*)d_in[8];
    const float* Wa = (const float*)d_in[9];
    const float* g1 = (const float*)d_in[10];
    const float* b1 = (const float*)d_in[11];
    const float* m1 = (const float*)d_in[12];
    const float* v1 = (const float*)d_in[13];
    const float* g2 = (const float*)d_in[14];
    const float* b2 = (const float*)d_in[15];
    const float* m2 = (const float*)d_in[16];
    const float* v2 = (const float*)d_in[17];

    float* wsf      = (float*)d_ws;
    float* bn_scale = wsf;            // 256
    float* bn_shift = wsf + 256;      // 256
    float* bkv      = wsf + 512;      // 512
    unsigned short* Wbf   = (unsigned short*)(wsf + 1024);          // 5*65536
    unsigned short* xbf   = Wbf + 5 * 65536;                        // [N,L,C]
    unsigned short* poolT = xbf   + (size_t)NBATCH * LEN * CH;      // [N,L2,C]
    unsigned short* xabf  = poolT + (size_t)NBATCH * LPOOL * CH;    // [N,L2,C]
    unsigned short* Kbf   = xabf  + (size_t)NBATCH * LPOOL * CH;    // [N,L2,C]
    unsigned short* Vbf   = Kbf   + (size_t)NBATCH * LPOOL * CH;    // [N,C,L2]
    unsigned short* Qbf   = Vbf   + (size_t)NBATCH * LPOOL * CH;    // [N,L,C]
    unsigned short* Obf   = Qbf   + (size_t)NBATCH * LEN * CH;      // [N,L,C]

    // 1. transpose+pool over x, weights->bf16, BN affine, bkv concat
    transpool_setup<<<1345, 256, 0, stream>>>(x, xbf, poolT,
        Wq, Wk, Wv, Wo, Wa, Wbf,
        g1, b1, m1, v1, g2, b2, m2, v2, bn_scale, bn_shift, bk, bv, bkv);

    // 2. q = Wq @ x + bq, pre-scaled by log2(e)/8 -> Qbf [N,L,C]
    gemm_mfma<<<dim3(32, 2, 4), 256, 0, stream>>>(
        Wbf + 0 * 65536, xbf, (size_t)LEN * CH, bq, nullptr, nullptr,
        nullptr, 0, Qbf, (size_t)LEN * CH, 256, nullptr, 0, 0, 1 << 30,
        LEN, 0.18033688f);

    // 3. xa = BN2(BN1(Wa @ pool(x))) -> xabf [N,L2,C]
    gemm_mfma<<<dim3(8, 2, 4), 256, 0, stream>>>(
        Wbf + 4 * 65536, poolT, (size_t)LPOOL * CH, nullptr, bn_scale, bn_shift,
        nullptr, 0, xabf, (size_t)LPOOL * CH, 256, nullptr, 0, 0, 1 << 30,
        LPOOL, 1.0f);

    // 4. fused k+v: A = [Wk;Wv] (contiguous in Wbf), M=512.
    //    rows 0..255 -> Kbf [l2][c] (mode1); rows 256..511 -> Vbf [c][l2] (mode2)
    gemm_mfma<<<dim3(8, 4, 4), 256, 0, stream>>>(
        Wbf + 1 * 65536, xabf, (size_t)LPOOL * CH, bkv, nullptr, nullptr,
        nullptr, 0, Kbf, (size_t)LPOOL * CH, 256, Vbf, (size_t)LPOOL * CH, LPOOL, 256,
        LPOOL, 1.0f);

    // 5. attention -> Obf [N,L,C] bf16
    //    (128-q blocks, 32 q/wave, async-DMA double-buffered K/V tiles)
    attn_mfma<<<dim3(LEN / 128, NH, NBATCH), 256, 0, stream>>>(Qbf, Kbf, Vbf, Obf);

    // 6. out = Wo @ o + bo -> f32 d_out [N,C,L]
    gemm_mfma<<<dim3(32, 2, 4), 256, 0, stream>>>(
        Wbf + 3 * 65536, Obf, (size_t)LEN * CH, bo, nullptr, nullptr,
        (float*)d_out, (size_t)CH * LEN, nullptr, 0, 0, nullptr, 0, 0, 1 << 30,
        LEN, 1.0f);
}

// Round 7
// 158.791 us; speedup vs baseline: 1.2695x; 1.0633x over previous
//
#include <hip/hip_runtime.h>
#include <stdint.h>

// Problem constants
constexpr int NBATCH = 4;
constexpr int CH     = 256;   // channels
constexpr int LEN    = 4096;  // sequence length
constexpr int LPOOL  = 1024;  // pooled length (LEN/4)
constexpr int NH     = 4;     // heads
constexpr int HD     = 64;    // head dim

typedef __attribute__((ext_vector_type(8))) short short8;     // 8 bf16 in 4 VGPRs
typedef __attribute__((ext_vector_type(4))) float float4e;    // MFMA C/D 16x16
typedef __attribute__((ext_vector_type(16))) float float16e;  // MFMA C/D 32x32
typedef __attribute__((ext_vector_type(2))) unsigned uint2v;

__device__ __forceinline__ unsigned short f2bf(float f) {
    union { unsigned int i; float f; } v; v.f = f;
    unsigned int lsb = (v.i >> 16) & 1u;
    v.i += 0x7fffu + lsb;
    return (unsigned short)(v.i >> 16);
}
// pack two floats -> two bf16 (round-half-up via +0x8000, then byte-perm)
__device__ __forceinline__ unsigned pack2bf(float lo, float hi) {
    unsigned a = __float_as_uint(lo) + 0x8000u;
    unsigned b = __float_as_uint(hi) + 0x8000u;
    return __builtin_amdgcn_perm(b, a, 0x07060302u);
}
// single-instruction 2^x (OCML exp2f without fast-math is ~12 VALU ops)
__device__ __forceinline__ float fast_exp2(float x) {
#if __has_builtin(__builtin_amdgcn_exp2f)
    return __builtin_amdgcn_exp2f(x);
#else
    float r;
    asm("v_exp_f32 %0, %1" : "=v"(r) : "v"(x));
    return r;
#endif
}
// async global->LDS DMA, 16B per lane; LDS dest = wave-uniform base + lane*16
__device__ __forceinline__ void gload16(const void* g, void* l) {
    __builtin_amdgcn_global_load_lds(
        (const __attribute__((address_space(1))) unsigned int*)g,
        (__attribute__((address_space(3))) unsigned int*)l, 16, 0, 0);
}

// ---------------------------------------------------------------------------
// Fused: blocks 0..1023 do transpose+pool over x; blocks 1024..1343 cast the
// 5 weight matrices to bf16; block 1344 computes BN affine + bkv concat.
__global__ __launch_bounds__(256) void transpool_setup(
    const float* __restrict__ x, unsigned short* __restrict__ xbf,
    unsigned short* __restrict__ poolT,
    const float* __restrict__ w0, const float* __restrict__ w1,
    const float* __restrict__ w2, const float* __restrict__ w3,
    const float* __restrict__ w4, unsigned short* __restrict__ outW,
    const float* __restrict__ g1, const float* __restrict__ b1,
    const float* __restrict__ m1, const float* __restrict__ v1,
    const float* __restrict__ g2, const float* __restrict__ b2,
    const float* __restrict__ m2, const float* __restrict__ v2,
    float* __restrict__ scale, float* __restrict__ shift,
    const float* __restrict__ bk, const float* __restrict__ bv,
    float* __restrict__ bkv)
{
    __shared__ float T[64][65];
    __shared__ float P16[64][17];
    int b = blockIdx.x, t = threadIdx.x;
    if (b >= 1024) {
        int sb = b - 1024;
        if (sb < 320) {
            int gid = sb * 256 + t;
            int w = gid >> 14;
            int off = (gid & 16383) * 4;
            const float* src = (w == 0) ? w0 : (w == 1) ? w1 : (w == 2) ? w2 : (w == 3) ? w3 : w4;
            float4 v = *(const float4*)(src + off);
            uint2 pk;
            pk.x = pack2bf(v.x, v.y);
            pk.y = pack2bf(v.z, v.w);
            *(uint2*)(outW + w * 65536 + off) = pk;
        } else {
            float inv1 = g1[t] * rsqrtf(v1[t] + 1e-5f);
            float inv2 = g2[t] * rsqrtf(v2[t] + 1e-5f);
            scale[t] = inv1 * inv2;
            shift[t] = (b1[t] - m1[t] * inv1) * inv2 + (b2[t] - m2[t] * inv2);
            bkv[t] = bk[t];
            bkv[256 + t] = bv[t];
        }
        return;
    }
    int n = b >> 8, c0 = ((b >> 6) & 3) * 64, l0 = (b & 63) * 64;
    const float* xp = x + ((size_t)n * CH + c0) * LEN + l0;
    #pragma unroll
    for (int i = 0; i < 4; i++) {
        int idx = t + i * 256;
        int c = idx >> 4, l4 = idx & 15;
        float4 v = *(const float4*)(xp + (size_t)c * LEN + l4 * 4);
        T[c][l4 * 4 + 0] = v.x; T[c][l4 * 4 + 1] = v.y;
        T[c][l4 * 4 + 2] = v.z; T[c][l4 * 4 + 3] = v.w;
        P16[c][l4] = (v.x + v.y + v.z + v.w) * 0.25f
                   + fmaxf(fmaxf(v.x, v.y), fmaxf(v.z, v.w));
    }
    __syncthreads();
    unsigned short* op = xbf + ((size_t)n * LEN + l0) * CH + c0;
    #pragma unroll
    for (int i = 0; i < 4; i++) {
        int idx = t + i * 256;
        int l = idx >> 4, c4 = idx & 15;
        uint2 pk;
        pk.x = pack2bf(T[c4 * 4 + 0][l], T[c4 * 4 + 1][l]);
        pk.y = pack2bf(T[c4 * 4 + 2][l], T[c4 * 4 + 3][l]);
        *(uint2*)(op + (size_t)l * CH + c4 * 4) = pk;
    }
    int p0 = l0 >> 2;
    #pragma unroll
    for (int k = 0; k < 2; k++) {
        int p = (t >> 5) + k * 8;
        int c2 = (t & 31) * 2;
        unsigned pk = pack2bf(P16[c2][p], P16[c2 + 1][p]);
        *(unsigned*)(poolT + ((size_t)n * LPOOL + p0 + p) * CH + c0 + c2) = pk;
    }
}

// ---------------------------------------------------------------------------
// MFMA GEMM, async-DMA pipelined (attn-proven T3/T4 schedule), BISECT BUILD:
// vs the failed r6 version, the LDS XOR swizzle is REMOVED (linear DMA
// source chunks + linear b128 reads) and the f32 epilogue restage uses
// exactly Bs (32 KB, exact size -- no cross-array aliasing). Geometry:
// BM=64 x BN=128, BK=64, K=256, double-buffered, one vmcnt(0)+s_barrier
// per K-step, grid 2x the old BM=128 version.
// D[i][j] = sum_k A[i][k]*B[j][k] (bf16, K-contig rows).
// Epilogue: + biasRow[i]; *scale[i]+shift[i]; *outScale.
// Output modes (per 64-row tile):
//   outF != 0                : f32 [row][col] (ld NN), LDS-restaged stores
//   rowTile <  rowSplit      : bf16 at out1 + col*cs1 + row
//   rowTile >= rowSplit      : bf16 at out2 + (row-rowSplit)*rs2 + col
__global__ __launch_bounds__(256, 2) void gemm_mfma(
    const unsigned short* __restrict__ A,
    const unsigned short* __restrict__ B, size_t bBatch,
    const float* __restrict__ biasRow,
    const float* __restrict__ scale, const float* __restrict__ shift,
    float* __restrict__ outF, size_t oFBatch,
    unsigned short* __restrict__ out1, size_t o1Batch, int cs1,
    unsigned short* __restrict__ out2, size_t o2Batch, int rs2, int rowSplit,
    int NN, float outScale)
{
    __shared__ unsigned short As[2][64 * 64];    // [row][k] linear, 8 KB each
    __shared__ unsigned short Bs[2][128 * 64];   // [col][k] linear, 16 KB each
    __shared__ unsigned short TO[128 * 72];      // bf16 epilogue restage (18 KB)

    int n = blockIdx.z;
    int t = threadIdx.x;
    int wave = t >> 6, lane = t & 63, m = lane & 15, quad = lane >> 4;
    int wm = wave & 1, wn = wave >> 1;
    int rowTile = blockIdx.y * 64;
    int col0 = blockIdx.x * 128;

    const unsigned short* Ab = A + (size_t)rowTile * 256;
    const unsigned short* Bb = B + (size_t)n * bBatch + (size_t)col0 * 256;

    float4e acc[2][4] = {};

    // staging: chunk idx = t + i*256; row = idx>>3, chunk-in-row = idx&7;
    // LDS dest byte = idx*16 (linear) = wave*1024 + i*4096 + lane*16.
    int arow[2], ach[2];
    #pragma unroll
    for (int i = 0; i < 2; i++) {
        int idx = t + i * 256;
        arow[i] = idx >> 3;
        ach[i]  = idx & 7;
    }
    int brow[4], bch[4];
    #pragma unroll
    for (int i = 0; i < 4; i++) {
        int idx = t + i * 256;
        brow[i] = idx >> 3;
        bch[i]  = idx & 7;
    }
    int ldsW[4];
    #pragma unroll
    for (int i = 0; i < 4; i++) ldsW[i] = wave * 1024 + i * 4096;

    // linear read byte-offsets: row r, k-chunk (kc*4+quad) of 16 B
    int aoff[2][2], boff[4][2];   // [frag][kc]
    #pragma unroll
    for (int i = 0; i < 2; i++) {
        int r = wm * 32 + i * 16 + m;
        #pragma unroll
        for (int kc = 0; kc < 2; kc++)
            aoff[i][kc] = r * 128 + kc * 64 + quad * 16;
    }
    #pragma unroll
    for (int j = 0; j < 4; j++) {
        int r = wn * 64 + j * 16 + m;
        #pragma unroll
        for (int kc = 0; kc < 2; kc++)
            boff[j][kc] = r * 128 + kc * 64 + quad * 16;
    }

    // prologue: DMA K-step 0 -> buf 0
    #pragma unroll
    for (int i = 0; i < 2; i++)
        gload16(Ab + (size_t)arow[i] * 256 + ach[i] * 8, (char*)As[0] + ldsW[i]);
    #pragma unroll
    for (int i = 0; i < 4; i++)
        gload16(Bb + (size_t)brow[i] * 256 + bch[i] * 8, (char*)Bs[0] + ldsW[i]);

    #pragma unroll
    for (int s = 0; s < 4; s++) {
        int cur = s & 1;
        // my K-step-s DMA complete; barrier => everyone's complete AND everyone
        // finished reading buf[cur^1] during step s-1
        asm volatile("s_waitcnt vmcnt(0)" ::: "memory");
        __builtin_amdgcn_sched_barrier(0);
        __builtin_amdgcn_s_barrier();
        __builtin_amdgcn_sched_barrier(0);
        // issue K-step s+1 DMA into the other buffer; flies under compute(s)
        if (s < 3) {
            int nxt = cur ^ 1;
            int kk = (s + 1) * 64;
            #pragma unroll
            for (int i = 0; i < 2; i++)
                gload16(Ab + (size_t)arow[i] * 256 + kk + ach[i] * 8, (char*)As[nxt] + ldsW[i]);
            #pragma unroll
            for (int i = 0; i < 4; i++)
                gload16(Bb + (size_t)brow[i] * 256 + kk + bch[i] * 8, (char*)Bs[nxt] + ldsW[i]);
        }
        const char* AsC = (const char*)As[cur];
        const char* BsC = (const char*)Bs[cur];
        #pragma unroll
        for (int kc = 0; kc < 2; kc++) {
            short8 af[2], bfr[4];
            #pragma unroll
            for (int i = 0; i < 2; i++)
                af[i] = *(const short8*)(AsC + aoff[i][kc]);
            #pragma unroll
            for (int j = 0; j < 4; j++)
                bfr[j] = *(const short8*)(BsC + boff[j][kc]);
            __builtin_amdgcn_s_setprio(1);
            #pragma unroll
            for (int i = 0; i < 2; i++)
                #pragma unroll
                for (int j = 0; j < 4; j++)
                    acc[i][j] = __builtin_amdgcn_mfma_f32_16x16x32_bf16(af[i], bfr[j], acc[i][j], 0, 0, 0);
            __builtin_amdgcn_s_setprio(0);
        }
    }
    __syncthreads();   // all waves done reading LDS; safe to reuse for epilogue

    if (outF) {
        float* TOf = (float*)Bs;   // 64 x 128 f32 = 32 KB = sizeof(Bs) exactly
        float* dst = outF + (size_t)n * oFBatch;
        #pragma unroll
        for (int i = 0; i < 2; i++) {
            int rowL = wm * 32 + i * 16 + quad * 4;
            int rowG = rowTile + rowL;
            float br[4], sc[4], sh[4];
            #pragma unroll
            for (int r = 0; r < 4; r++) {
                br[r] = biasRow ? biasRow[rowG + r] : 0.0f;
                sc[r] = scale ? scale[rowG + r] : 1.0f;
                sh[r] = shift ? shift[rowG + r] : 0.0f;
            }
            #pragma unroll
            for (int j = 0; j < 4; j++) {
                int colL = wn * 64 + j * 16 + m;
                float4e c = acc[i][j];
                #pragma unroll
                for (int r = 0; r < 4; r++)
                    TOf[(rowL + r) * 128 + colL] = ((c[r] + br[r]) * sc[r] + sh[r]) * outScale;
            }
        }
        __syncthreads();
        #pragma unroll
        for (int w = 0; w < 8; w++) {
            int idx = t + w * 256;
            int row = idx >> 5, c4 = idx & 31;
            *(float4*)(dst + (size_t)(rowTile + row) * NN + col0 + c4 * 4) =
                *(const float4*)&TOf[row * 128 + c4 * 4];
        }
        return;
    }

    bool mode2 = (rowTile >= rowSplit);
    #pragma unroll
    for (int i = 0; i < 2; i++) {
        int rowL = wm * 32 + i * 16 + quad * 4;
        int rowG = rowTile + rowL;
        float br[4], sc[4], sh[4];
        #pragma unroll
        for (int r = 0; r < 4; r++) {
            br[r] = biasRow ? biasRow[rowG + r] : 0.0f;
            sc[r] = scale ? scale[rowG + r] : 1.0f;
            sh[r] = shift ? shift[rowG + r] : 0.0f;
        }
        #pragma unroll
        for (int j = 0; j < 4; j++) {
            int colL = wn * 64 + j * 16 + m;
            float4e c = acc[i][j];
            float v0 = ((c[0] + br[0]) * sc[0] + sh[0]) * outScale;
            float v1 = ((c[1] + br[1]) * sc[1] + sh[1]) * outScale;
            float v2 = ((c[2] + br[2]) * sc[2] + sh[2]) * outScale;
            float v3 = ((c[3] + br[3]) * sc[3] + sh[3]) * outScale;
            if (!mode2) {
                uint2 pk;
                pk.x = pack2bf(v0, v1);
                pk.y = pack2bf(v2, v3);
                *(uint2*)&TO[colL * 72 + rowL] = pk;
            } else {
                TO[(rowL + 0) * 136 + colL] = f2bf(v0);
                TO[(rowL + 1) * 136 + colL] = f2bf(v1);
                TO[(rowL + 2) * 136 + colL] = f2bf(v2);
                TO[(rowL + 3) * 136 + colL] = f2bf(v3);
            }
        }
    }
    __syncthreads();
    if (!mode2) {
        unsigned short* dst = out1 + (size_t)n * o1Batch;
        #pragma unroll
        for (int w = 0; w < 4; w++) {
            int idx = t + w * 256;
            int l = idx >> 3, ch = idx & 7;
            *(uint4*)(dst + (size_t)(col0 + l) * cs1 + rowTile + ch * 8) =
                *(const uint4*)&TO[l * 72 + ch * 8];
        }
    } else {
        unsigned short* dst = out2 + (size_t)n * o2Batch;
        int rowBase = rowTile - rowSplit;
        #pragma unroll
        for (int w = 0; w < 4; w++) {
            int idx = t + w * 256;
            int row = idx >> 4, ch = idx & 15;
            *(uint4*)(dst + (size_t)(rowBase + row) * rs2 + col0 + ch * 8) =
                *(const uint4*)&TO[row * 136 + ch * 8];
        }
    }
}

// ---------------------------------------------------------------------------
// MFMA flash attention, 32x32x16, async-DMA pipelined (T3/T4). Byte-identical
// to the passing round-5 version (attn dropped below the 43.5 us fillBuffer
// floor there). Do not touch.
__global__ __launch_bounds__(256, 2) void attn_mfma(
    const unsigned short* __restrict__ Qb,
    const unsigned short* __restrict__ Kb,
    const unsigned short* __restrict__ Vb,
    unsigned short* __restrict__ Obf)
{
    __shared__ unsigned short Ks[2][64 * 64];   // [key][dim], swizzled content
    __shared__ unsigned short Vs[2][64 * 64];   // [e][key],  swizzled content

    int qb = blockIdx.x;          // 128-row q block
    int h  = blockIdx.y;
    int n  = blockIdx.z;
    int t  = threadIdx.x;
    int wave = t >> 6, lane = t & 63;
    int col = lane & 31;          // q within wave
    int hi  = lane >> 5;
    int l0 = qb * 128 + wave * 32;

    // Q B-frags: lane holds q=col, dims dc*16 + hi*8 .. +7
    const unsigned short* qp = Qb + ((size_t)n * LEN + l0 + col) * CH + h * HD + hi * 8;
    short8 bQ[4];
    #pragma unroll
    for (int dc = 0; dc < 4; dc++)
        bQ[dc] = *(const short8*)(qp + dc * 16);

    float16e Oa[2];
    #pragma unroll
    for (int e = 0; e < 2; e++)
        #pragma unroll
        for (int r = 0; r < 16; r++) Oa[e][r] = 0.0f;
    float l_run = 0.0f;

    const unsigned short* KgBase = Kb + (size_t)n * LPOOL * CH + h * HD;
    const unsigned short* VgBase = Vb + ((size_t)n * CH + h * HD) * LPOOL;
    const float NEG = -17.312340f;   // -12 * log2(e)

    int srow[2], schs[2], ldsb[2];
    #pragma unroll
    for (int i = 0; i < 2; i++) {
        int idx = t + i * 256;
        srow[i] = idx >> 3;
        schs[i] = (idx & 7) ^ (srow[i] & 7);
        ldsb[i] = wave * 1024 + i * 4096;   // wave-uniform DMA base (bytes)
    }
    int ldoff[2][4];
    #pragma unroll
    for (int g = 0; g < 2; g++)
        #pragma unroll
        for (int c = 0; c < 4; c++) {
            int row = g * 32 + col;
            ldoff[g][c] = row * 128 + ((c * 32 + hi * 16) ^ ((row & 7) << 4));
        }

    // prologue: DMA tile 0 -> buf 0
    #pragma unroll
    for (int i = 0; i < 2; i++) {
        gload16(KgBase + (size_t)srow[i] * CH + schs[i] * 8, (char*)Ks[0] + ldsb[i]);
        gload16(VgBase + (size_t)srow[i] * LPOOL + schs[i] * 8, (char*)Vs[0] + ldsb[i]);
    }

    #pragma unroll 2
    for (int kt = 0; kt < 16; kt++) {
        int cur = kt & 1;
        asm volatile("s_waitcnt vmcnt(0)" ::: "memory");
        __builtin_amdgcn_sched_barrier(0);
        __builtin_amdgcn_s_barrier();
        __builtin_amdgcn_sched_barrier(0);
        if (kt < 15) {
            int nxt = cur ^ 1;
            const unsigned short* ksrc = KgBase + (size_t)(kt + 1) * 64 * CH;
            const unsigned short* vsrc = VgBase + (kt + 1) * 64;
            #pragma unroll
            for (int i = 0; i < 2; i++) {
                gload16(ksrc + (size_t)srow[i] * CH + schs[i] * 8, (char*)Ks[nxt] + ldsb[i]);
                gload16(vsrc + (size_t)srow[i] * LPOOL + schs[i] * 8, (char*)Vs[nxt] + ldsb[i]);
            }
        }

        const char* KsC = (const char*)Ks[cur];
        const char* VsC = (const char*)Vs[cur];
        #pragma unroll
        for (int kh = 0; kh < 2; kh++) {
            float16e c;
            #pragma unroll
            for (int r = 0; r < 16; r++) c[r] = NEG;
            __builtin_amdgcn_s_setprio(1);
            #pragma unroll
            for (int dc = 0; dc < 4; dc++) {
                short8 a = *(const short8*)(KsC + ldoff[kh][dc]);
                c = __builtin_amdgcn_mfma_f32_32x32x16_bf16(a, bQ[dc], c, 0, 0, 0);
            }
            __builtin_amdgcn_s_setprio(0);
            float p[16];
            #pragma unroll
            for (int r = 0; r < 16; r++) p[r] = fast_exp2(c[r]);
            l_run += ((p[0] + p[1]) + (p[2] + p[3])) + ((p[4] + p[5]) + (p[6] + p[7]))
                   + ((p[8] + p[9]) + (p[10] + p[11])) + ((p[12] + p[13]) + (p[14] + p[15]));
            union { unsigned u[4]; short8 s; } bP[2];
            #pragma unroll
            for (int kc2 = 0; kc2 < 2; kc2++) {
                int rb = kc2 * 8;
                unsigned A0 = pack2bf(p[rb + 0], p[rb + 1]);
                unsigned B0 = pack2bf(p[rb + 4], p[rb + 5]);
                unsigned A1 = pack2bf(p[rb + 2], p[rb + 3]);
                unsigned B1 = pack2bf(p[rb + 6], p[rb + 7]);
                uint2v s0 = __builtin_amdgcn_permlane32_swap(A0, B0, false, false);
                uint2v s1 = __builtin_amdgcn_permlane32_swap(A1, B1, false, false);
                bP[kc2].u[0] = s0[0];
                bP[kc2].u[1] = s1[0];
                bP[kc2].u[2] = s0[1];
                bP[kc2].u[3] = s1[1];
            }
            __builtin_amdgcn_s_setprio(1);
            #pragma unroll
            for (int eh = 0; eh < 2; eh++)
                #pragma unroll
                for (int kc2 = 0; kc2 < 2; kc2++) {
                    short8 av = *(const short8*)(VsC + ldoff[eh][kh * 2 + kc2]);
                    Oa[eh] = __builtin_amdgcn_mfma_f32_32x32x16_bf16(av, bP[kc2].s, Oa[eh], 0, 0, 0);
                }
            __builtin_amdgcn_s_setprio(0);
        }
    }

    // normalize + store: e = (r&3) + 8*(r>>2) + 4*hi + 32*eh
    float l = l_run + __shfl_xor(l_run, 32);
    float inv = 1.0f / l;
    unsigned short* op = Obf + ((size_t)n * LEN + l0 + col) * CH + h * HD + hi * 4;
    #pragma unroll
    for (int eh = 0; eh < 2; eh++)
        #pragma unroll
        for (int rq = 0; rq < 4; rq++) {
            int r = rq * 4;
            uint2 pk;
            pk.x = pack2bf(Oa[eh][r + 0] * inv, Oa[eh][r + 1] * inv);
            pk.y = pack2bf(Oa[eh][r + 2] * inv, Oa[eh][r + 3] * inv);
            *(uint2*)(op + eh * 32 + rq * 8) = pk;
        }
}

// ---------------------------------------------------------------------------
extern "C" void kernel_launch(void* const* d_in, const int* in_sizes, int n_in,
                              void* d_out, int out_size, void* d_ws, size_t ws_size,
                              hipStream_t stream)
{
    const float* x  = (const float*)d_in[0];
    const float* Wq = (const float*)d_in[1];
    const float* bq = (const float*)d_in[2];
    const float* Wk = (const float*)d_in[3];
    const float* bk = (const float*)d_in[4];
    const float* Wv = (const float*)d_in[5];
    const float* bv = (const float*)d_in[6];
    const float* Wo = (const float*)d_in[7];
    const float* bo = (const float*)d_in[8];
    const float* Wa = (const float*)d_in[9];
    const float* g1 = (const float*)d_in[10];
    const float* b1 = (const float*)d_in[11];
    const float* m1 = (const float*)d_in[12];
    const float* v1 = (const float*)d_in[13];
    const float* g2 = (const float*)d_in[14];
    const float* b2 = (const float*)d_in[15];
    const float* m2 = (const float*)d_in[16];
    const float* v2 = (const float*)d_in[17];

    float* wsf      = (float*)d_ws;
    float* bn_scale = wsf;            // 256
    float* bn_shift = wsf + 256;      // 256
    float* bkv      = wsf + 512;      // 512
    unsigned short* Wbf   = (unsigned short*)(wsf + 1024);          // 5*65536
    unsigned short* xbf   = Wbf + 5 * 65536;                        // [N,L,C]
    unsigned short* poolT = xbf   + (size_t)NBATCH * LEN * CH;      // [N,L2,C]
    unsigned short* xabf  = poolT + (size_t)NBATCH * LPOOL * CH;    // [N,L2,C]
    unsigned short* Kbf   = xabf  + (size_t)NBATCH * LPOOL * CH;    // [N,L2,C]
    unsigned short* Vbf   = Kbf   + (size_t)NBATCH * LPOOL * CH;    // [N,C,L2]
    unsigned short* Qbf   = Vbf   + (size_t)NBATCH * LPOOL * CH;    // [N,L,C]
    unsigned short* Obf   = Qbf   + (size_t)NBATCH * LEN * CH;      // [N,L,C]

    // 1. transpose+pool over x, weights->bf16, BN affine, bkv concat
    transpool_setup<<<1345, 256, 0, stream>>>(x, xbf, poolT,
        Wq, Wk, Wv, Wo, Wa, Wbf,
        g1, b1, m1, v1, g2, b2, m2, v2, bn_scale, bn_shift, bk, bv, bkv);

    // 2. q = Wq @ x + bq, pre-scaled by log2(e)/8 -> Qbf [N,L,C]
    gemm_mfma<<<dim3(32, 4, 4), 256, 0, stream>>>(
        Wbf + 0 * 65536, xbf, (size_t)LEN * CH, bq, nullptr, nullptr,
        nullptr, 0, Qbf, (size_t)LEN * CH, 256, nullptr, 0, 0, 1 << 30,
        LEN, 0.18033688f);

    // 3. xa = BN2(BN1(Wa @ pool(x))) -> xabf [N,L2,C]
    gemm_mfma<<<dim3(8, 4, 4), 256, 0, stream>>>(
        Wbf + 4 * 65536, poolT, (size_t)LPOOL * CH, nullptr, bn_scale, bn_shift,
        nullptr, 0, xabf, (size_t)LPOOL * CH, 256, nullptr, 0, 0, 1 << 30,
        LPOOL, 1.0f);

    // 4. fused k+v: A = [Wk;Wv] (contiguous in Wbf), M=512.
    //    rows 0..255 -> Kbf [l2][c] (mode1); rows 256..511 -> Vbf [c][l2] (mode2)
    gemm_mfma<<<dim3(8, 8, 4), 256, 0, stream>>>(
        Wbf + 1 * 65536, xabf, (size_t)LPOOL * CH, bkv, nullptr, nullptr,
        nullptr, 0, Kbf, (size_t)LPOOL * CH, 256, Vbf, (size_t)LPOOL * CH, LPOOL, 256,
        LPOOL, 1.0f);

    // 5. attention -> Obf [N,L,C] bf16
    //    (128-q blocks, 32 q/wave, async-DMA double-buffered K/V tiles)
    attn_mfma<<<dim3(LEN / 128, NH, NBATCH), 256, 0, stream>>>(Qbf, Kbf, Vbf, Obf);

    // 6. out = Wo @ o + bo -> f32 d_out [N,C,L]
    gemm_mfma<<<dim3(32, 4, 4), 256, 0, stream>>>(
        Wbf + 3 * 65536, Obf, (size_t)LEN * CH, bo, nullptr, nullptr,
        (float*)d_out, (size_t)CH * LEN, nullptr, 0, 0, nullptr, 0, 0, 1 << 30,
        LEN, 1.0f);
}

// Round 8
// 156.871 us; speedup vs baseline: 1.2850x; 1.0122x over previous
//
#include <hip/hip_runtime.h>
#include <stdint.h>

// Problem constants
constexpr int NBATCH = 4;
constexpr int CH     = 256;   // channels
constexpr int LEN    = 4096;  // sequence length
constexpr int LPOOL  = 1024;  // pooled length (LEN/4)
constexpr int NH     = 4;     // heads
constexpr int HD     = 64;    // head dim

typedef __attribute__((ext_vector_type(8))) short short8;     // 8 bf16 in 4 VGPRs
typedef __attribute__((ext_vector_type(4))) float float4e;    // MFMA C/D 16x16
typedef __attribute__((ext_vector_type(16))) float float16e;  // MFMA C/D 32x32
typedef __attribute__((ext_vector_type(2))) unsigned uint2v;

__device__ __forceinline__ unsigned short f2bf(float f) {
    union { unsigned int i; float f; } v; v.f = f;
    unsigned int lsb = (v.i >> 16) & 1u;
    v.i += 0x7fffu + lsb;
    return (unsigned short)(v.i >> 16);
}
// pack two floats -> two bf16 (round-half-up via +0x8000, then byte-perm)
__device__ __forceinline__ unsigned pack2bf(float lo, float hi) {
    unsigned a = __float_as_uint(lo) + 0x8000u;
    unsigned b = __float_as_uint(hi) + 0x8000u;
    return __builtin_amdgcn_perm(b, a, 0x07060302u);
}
// single-instruction 2^x (OCML exp2f without fast-math is ~12 VALU ops)
__device__ __forceinline__ float fast_exp2(float x) {
#if __has_builtin(__builtin_amdgcn_exp2f)
    return __builtin_amdgcn_exp2f(x);
#else
    float r;
    asm("v_exp_f32 %0, %1" : "=v"(r) : "v"(x));
    return r;
#endif
}
// async global->LDS DMA, 16B per lane; LDS dest = wave-uniform base + lane*16
__device__ __forceinline__ void gload16(const void* g, void* l) {
    __builtin_amdgcn_global_load_lds(
        (const __attribute__((address_space(1))) unsigned int*)g,
        (__attribute__((address_space(3))) unsigned int*)l, 16, 0, 0);
}

// ---------------------------------------------------------------------------
// Fused: blocks 0..1023 do transpose+pool over x; blocks 1024..1343 cast the
// 5 weight matrices to bf16; block 1344 computes BN affine + bkv concat.
__global__ __launch_bounds__(256) void transpool_setup(
    const float* __restrict__ x, unsigned short* __restrict__ xbf,
    unsigned short* __restrict__ poolT,
    const float* __restrict__ w0, const float* __restrict__ w1,
    const float* __restrict__ w2, const float* __restrict__ w3,
    const float* __restrict__ w4, unsigned short* __restrict__ outW,
    const float* __restrict__ g1, const float* __restrict__ b1,
    const float* __restrict__ m1, const float* __restrict__ v1,
    const float* __restrict__ g2, const float* __restrict__ b2,
    const float* __restrict__ m2, const float* __restrict__ v2,
    float* __restrict__ scale, float* __restrict__ shift,
    const float* __restrict__ bk, const float* __restrict__ bv,
    float* __restrict__ bkv)
{
    __shared__ float T[64][65];
    __shared__ float P16[64][17];
    int b = blockIdx.x, t = threadIdx.x;
    if (b >= 1024) {
        int sb = b - 1024;
        if (sb < 320) {
            int gid = sb * 256 + t;
            int w = gid >> 14;
            int off = (gid & 16383) * 4;
            const float* src = (w == 0) ? w0 : (w == 1) ? w1 : (w == 2) ? w2 : (w == 3) ? w3 : w4;
            float4 v = *(const float4*)(src + off);
            uint2 pk;
            pk.x = pack2bf(v.x, v.y);
            pk.y = pack2bf(v.z, v.w);
            *(uint2*)(outW + w * 65536 + off) = pk;
        } else {
            float inv1 = g1[t] * rsqrtf(v1[t] + 1e-5f);
            float inv2 = g2[t] * rsqrtf(v2[t] + 1e-5f);
            scale[t] = inv1 * inv2;
            shift[t] = (b1[t] - m1[t] * inv1) * inv2 + (b2[t] - m2[t] * inv2);
            bkv[t] = bk[t];
            bkv[256 + t] = bv[t];
        }
        return;
    }
    int n = b >> 8, c0 = ((b >> 6) & 3) * 64, l0 = (b & 63) * 64;
    const float* xp = x + ((size_t)n * CH + c0) * LEN + l0;
    #pragma unroll
    for (int i = 0; i < 4; i++) {
        int idx = t + i * 256;
        int c = idx >> 4, l4 = idx & 15;
        float4 v = *(const float4*)(xp + (size_t)c * LEN + l4 * 4);
        T[c][l4 * 4 + 0] = v.x; T[c][l4 * 4 + 1] = v.y;
        T[c][l4 * 4 + 2] = v.z; T[c][l4 * 4 + 3] = v.w;
        P16[c][l4] = (v.x + v.y + v.z + v.w) * 0.25f
                   + fmaxf(fmaxf(v.x, v.y), fmaxf(v.z, v.w));
    }
    __syncthreads();
    unsigned short* op = xbf + ((size_t)n * LEN + l0) * CH + c0;
    #pragma unroll
    for (int i = 0; i < 4; i++) {
        int idx = t + i * 256;
        int l = idx >> 4, c4 = idx & 15;
        uint2 pk;
        pk.x = pack2bf(T[c4 * 4 + 0][l], T[c4 * 4 + 1][l]);
        pk.y = pack2bf(T[c4 * 4 + 2][l], T[c4 * 4 + 3][l]);
        *(uint2*)(op + (size_t)l * CH + c4 * 4) = pk;
    }
    int p0 = l0 >> 2;
    #pragma unroll
    for (int k = 0; k < 2; k++) {
        int p = (t >> 5) + k * 8;
        int c2 = (t & 31) * 2;
        unsigned pk = pack2bf(P16[c2][p], P16[c2 + 1][p]);
        *(unsigned*)(poolT + ((size_t)n * LPOOL + p0 + p) * CH + c0 + c2) = pk;
    }
}

// ---------------------------------------------------------------------------
// MFMA GEMM, async-DMA pipelined (r7-proven schedule), occupancy build:
// BM=64 x BN=64 tiles (was 64x128): LDS 32 KB (As 2x8KB + Bs 2x8KB, epilogue
// restage reuses Bs exactly -- f32 tile = 16 KB = sizeof(Bs)), grid doubles
// (q/o-proj 1024 blocks = 4 blocks/CU = 4 waves/SIMD, 2x TLP). Schedule per
// K-step unchanged: vmcnt(0) ; s_barrier ; issue DMA(s+1) ; compute(s).
// Staging 4 gload16/thread/K-step (2 A + 2 B), linear layout (no swizzle).
// D[i][j] = sum_k A[i][k]*B[j][k] (bf16, K-contig rows), K=256, BK=64.
// Epilogue: + biasRow[i]; *scale[i]+shift[i]; *outScale.
// Output modes (per 64-row tile):
//   outF != 0                : f32 [row][col] (ld NN), LDS-restaged stores
//   rowTile <  rowSplit      : bf16 at out1 + col*cs1 + row
//   rowTile >= rowSplit      : bf16 at out2 + (row-rowSplit)*rs2 + col
__global__ __launch_bounds__(256, 4) void gemm_mfma(
    const unsigned short* __restrict__ A,
    const unsigned short* __restrict__ B, size_t bBatch,
    const float* __restrict__ biasRow,
    const float* __restrict__ scale, const float* __restrict__ shift,
    float* __restrict__ outF, size_t oFBatch,
    unsigned short* __restrict__ out1, size_t o1Batch, int cs1,
    unsigned short* __restrict__ out2, size_t o2Batch, int rs2, int rowSplit,
    int NN, float outScale)
{
    __shared__ unsigned short As[2][64 * 64];    // [row][k] linear, 8 KB each
    __shared__ unsigned short Bs[2][64 * 64];    // [col][k] linear, 8 KB each

    int n = blockIdx.z;
    int t = threadIdx.x;
    int wave = t >> 6, lane = t & 63, m = lane & 15, quad = lane >> 4;
    int wm = wave & 1, wn = wave >> 1;           // row-half / col-half (32 each)
    int rowTile = blockIdx.y * 64;
    int col0 = blockIdx.x * 64;

    const unsigned short* Ab = A + (size_t)rowTile * 256;
    const unsigned short* Bb = B + (size_t)n * bBatch + (size_t)col0 * 256;

    float4e acc[2][2] = {};

    // staging: chunk idx = t + i*256 (i<2); row = idx>>3, chunk-in-row = idx&7;
    // LDS dest byte = idx*16 (linear) = wave*1024 + i*4096 + lane*16.
    int srow[2], sch[2], ldsW[2];
    #pragma unroll
    for (int i = 0; i < 2; i++) {
        int idx = t + i * 256;
        srow[i] = idx >> 3;
        sch[i]  = idx & 7;
        ldsW[i] = wave * 1024 + i * 4096;
    }

    // linear read byte-offsets: row r, k-chunk (kc*4+quad) of 16 B
    int aoff[2][2], boff[2][2];   // [frag][kc]
    #pragma unroll
    for (int i = 0; i < 2; i++) {
        int ra = wm * 32 + i * 16 + m;
        int rb = wn * 32 + i * 16 + m;
        #pragma unroll
        for (int kc = 0; kc < 2; kc++) {
            aoff[i][kc] = ra * 128 + kc * 64 + quad * 16;
            boff[i][kc] = rb * 128 + kc * 64 + quad * 16;
        }
    }

    // prologue: DMA K-step 0 -> buf 0
    #pragma unroll
    for (int i = 0; i < 2; i++) {
        gload16(Ab + (size_t)srow[i] * 256 + sch[i] * 8, (char*)As[0] + ldsW[i]);
        gload16(Bb + (size_t)srow[i] * 256 + sch[i] * 8, (char*)Bs[0] + ldsW[i]);
    }

    #pragma unroll
    for (int s = 0; s < 4; s++) {
        int cur = s & 1;
        // my K-step-s DMA complete; barrier => everyone's complete AND everyone
        // finished reading buf[cur^1] during step s-1
        asm volatile("s_waitcnt vmcnt(0)" ::: "memory");
        __builtin_amdgcn_sched_barrier(0);
        __builtin_amdgcn_s_barrier();
        __builtin_amdgcn_sched_barrier(0);
        // issue K-step s+1 DMA into the other buffer; flies under compute(s)
        if (s < 3) {
            int nxt = cur ^ 1;
            int kk = (s + 1) * 64;
            #pragma unroll
            for (int i = 0; i < 2; i++) {
                gload16(Ab + (size_t)srow[i] * 256 + kk + sch[i] * 8, (char*)As[nxt] + ldsW[i]);
                gload16(Bb + (size_t)srow[i] * 256 + kk + sch[i] * 8, (char*)Bs[nxt] + ldsW[i]);
            }
        }
        const char* AsC = (const char*)As[cur];
        const char* BsC = (const char*)Bs[cur];
        #pragma unroll
        for (int kc = 0; kc < 2; kc++) {
            short8 af[2], bfr[2];
            #pragma unroll
            for (int i = 0; i < 2; i++) {
                af[i]  = *(const short8*)(AsC + aoff[i][kc]);
                bfr[i] = *(const short8*)(BsC + boff[i][kc]);
            }
            __builtin_amdgcn_s_setprio(1);
            #pragma unroll
            for (int i = 0; i < 2; i++)
                #pragma unroll
                for (int j = 0; j < 2; j++)
                    acc[i][j] = __builtin_amdgcn_mfma_f32_16x16x32_bf16(af[i], bfr[j], acc[i][j], 0, 0, 0);
            __builtin_amdgcn_s_setprio(0);
        }
    }
    __syncthreads();   // all waves done reading LDS; safe to reuse Bs for epilogue

    if (outF) {
        float* TOf = (float*)Bs;   // 64 x 64 f32 = 16 KB = sizeof(Bs) exactly
        float* dst = outF + (size_t)n * oFBatch;
        #pragma unroll
        for (int i = 0; i < 2; i++) {
            int rowL = wm * 32 + i * 16 + quad * 4;
            int rowG = rowTile + rowL;
            float br[4], sc[4], sh[4];
            #pragma unroll
            for (int r = 0; r < 4; r++) {
                br[r] = biasRow ? biasRow[rowG + r] : 0.0f;
                sc[r] = scale ? scale[rowG + r] : 1.0f;
                sh[r] = shift ? shift[rowG + r] : 0.0f;
            }
            #pragma unroll
            for (int j = 0; j < 2; j++) {
                int colL = wn * 32 + j * 16 + m;
                float4e c = acc[i][j];
                #pragma unroll
                for (int r = 0; r < 4; r++)
                    TOf[(rowL + r) * 64 + colL] = ((c[r] + br[r]) * sc[r] + sh[r]) * outScale;
            }
        }
        __syncthreads();
        #pragma unroll
        for (int w = 0; w < 4; w++) {
            int idx = t + w * 256;
            int row = idx >> 4, c4 = idx & 15;
            *(float4*)(dst + (size_t)(rowTile + row) * NN + col0 + c4 * 4) =
                *(const float4*)&TOf[row * 64 + c4 * 4];
        }
        return;
    }

    bool mode2 = (rowTile >= rowSplit);
    unsigned short* TO = (unsigned short*)Bs;   // <= 9.2 KB used, 16 KB available
    #pragma unroll
    for (int i = 0; i < 2; i++) {
        int rowL = wm * 32 + i * 16 + quad * 4;
        int rowG = rowTile + rowL;
        float br[4], sc[4], sh[4];
        #pragma unroll
        for (int r = 0; r < 4; r++) {
            br[r] = biasRow ? biasRow[rowG + r] : 0.0f;
            sc[r] = scale ? scale[rowG + r] : 1.0f;
            sh[r] = shift ? shift[rowG + r] : 0.0f;
        }
        #pragma unroll
        for (int j = 0; j < 2; j++) {
            int colL = wn * 32 + j * 16 + m;
            float4e c = acc[i][j];
            float v0 = ((c[0] + br[0]) * sc[0] + sh[0]) * outScale;
            float v1 = ((c[1] + br[1]) * sc[1] + sh[1]) * outScale;
            float v2 = ((c[2] + br[2]) * sc[2] + sh[2]) * outScale;
            float v3 = ((c[3] + br[3]) * sc[3] + sh[3]) * outScale;
            if (!mode2) {
                uint2 pk;
                pk.x = pack2bf(v0, v1);
                pk.y = pack2bf(v2, v3);
                *(uint2*)&TO[colL * 72 + rowL] = pk;
            } else {
                TO[(rowL + 0) * 72 + colL] = f2bf(v0);
                TO[(rowL + 1) * 72 + colL] = f2bf(v1);
                TO[(rowL + 2) * 72 + colL] = f2bf(v2);
                TO[(rowL + 3) * 72 + colL] = f2bf(v3);
            }
        }
    }
    __syncthreads();
    if (!mode2) {
        unsigned short* dst = out1 + (size_t)n * o1Batch;
        #pragma unroll
        for (int w = 0; w < 2; w++) {
            int idx = t + w * 256;
            int l = idx >> 3, ch = idx & 7;
            *(uint4*)(dst + (size_t)(col0 + l) * cs1 + rowTile + ch * 8) =
                *(const uint4*)&TO[l * 72 + ch * 8];
        }
    } else {
        unsigned short* dst = out2 + (size_t)n * o2Batch;
        int rowBase = rowTile - rowSplit;
        #pragma unroll
        for (int w = 0; w < 2; w++) {
            int idx = t + w * 256;
            int row = idx >> 3, ch = idx & 7;
            *(uint4*)(dst + (size_t)(rowBase + row) * rs2 + col0 + ch * 8) =
                *(const uint4*)&TO[row * 72 + ch * 8];
        }
    }
}

// ---------------------------------------------------------------------------
// MFMA flash attention, 32x32x16, async-DMA pipelined (T3/T4). Byte-identical
// to the passing round-5/7 version. Do not touch.
__global__ __launch_bounds__(256, 2) void attn_mfma(
    const unsigned short* __restrict__ Qb,
    const unsigned short* __restrict__ Kb,
    const unsigned short* __restrict__ Vb,
    unsigned short* __restrict__ Obf)
{
    __shared__ unsigned short Ks[2][64 * 64];   // [key][dim], swizzled content
    __shared__ unsigned short Vs[2][64 * 64];   // [e][key],  swizzled content

    int qb = blockIdx.x;          // 128-row q block
    int h  = blockIdx.y;
    int n  = blockIdx.z;
    int t  = threadIdx.x;
    int wave = t >> 6, lane = t & 63;
    int col = lane & 31;          // q within wave
    int hi  = lane >> 5;
    int l0 = qb * 128 + wave * 32;

    // Q B-frags: lane holds q=col, dims dc*16 + hi*8 .. +7
    const unsigned short* qp = Qb + ((size_t)n * LEN + l0 + col) * CH + h * HD + hi * 8;
    short8 bQ[4];
    #pragma unroll
    for (int dc = 0; dc < 4; dc++)
        bQ[dc] = *(const short8*)(qp + dc * 16);

    float16e Oa[2];
    #pragma unroll
    for (int e = 0; e < 2; e++)
        #pragma unroll
        for (int r = 0; r < 16; r++) Oa[e][r] = 0.0f;
    float l_run = 0.0f;

    const unsigned short* KgBase = Kb + (size_t)n * LPOOL * CH + h * HD;
    const unsigned short* VgBase = Vb + ((size_t)n * CH + h * HD) * LPOOL;
    const float NEG = -17.312340f;   // -12 * log2(e)

    int srow[2], schs[2], ldsb[2];
    #pragma unroll
    for (int i = 0; i < 2; i++) {
        int idx = t + i * 256;
        srow[i] = idx >> 3;
        schs[i] = (idx & 7) ^ (srow[i] & 7);
        ldsb[i] = wave * 1024 + i * 4096;   // wave-uniform DMA base (bytes)
    }
    int ldoff[2][4];
    #pragma unroll
    for (int g = 0; g < 2; g++)
        #pragma unroll
        for (int c = 0; c < 4; c++) {
            int row = g * 32 + col;
            ldoff[g][c] = row * 128 + ((c * 32 + hi * 16) ^ ((row & 7) << 4));
        }

    // prologue: DMA tile 0 -> buf 0
    #pragma unroll
    for (int i = 0; i < 2; i++) {
        gload16(KgBase + (size_t)srow[i] * CH + schs[i] * 8, (char*)Ks[0] + ldsb[i]);
        gload16(VgBase + (size_t)srow[i] * LPOOL + schs[i] * 8, (char*)Vs[0] + ldsb[i]);
    }

    #pragma unroll 2
    for (int kt = 0; kt < 16; kt++) {
        int cur = kt & 1;
        asm volatile("s_waitcnt vmcnt(0)" ::: "memory");
        __builtin_amdgcn_sched_barrier(0);
        __builtin_amdgcn_s_barrier();
        __builtin_amdgcn_sched_barrier(0);
        if (kt < 15) {
            int nxt = cur ^ 1;
            const unsigned short* ksrc = KgBase + (size_t)(kt + 1) * 64 * CH;
            const unsigned short* vsrc = VgBase + (kt + 1) * 64;
            #pragma unroll
            for (int i = 0; i < 2; i++) {
                gload16(ksrc + (size_t)srow[i] * CH + schs[i] * 8, (char*)Ks[nxt] + ldsb[i]);
                gload16(vsrc + (size_t)srow[i] * LPOOL + schs[i] * 8, (char*)Vs[nxt] + ldsb[i]);
            }
        }

        const char* KsC = (const char*)Ks[cur];
        const char* VsC = (const char*)Vs[cur];
        #pragma unroll
        for (int kh = 0; kh < 2; kh++) {
            float16e c;
            #pragma unroll
            for (int r = 0; r < 16; r++) c[r] = NEG;
            __builtin_amdgcn_s_setprio(1);
            #pragma unroll
            for (int dc = 0; dc < 4; dc++) {
                short8 a = *(const short8*)(KsC + ldoff[kh][dc]);
                c = __builtin_amdgcn_mfma_f32_32x32x16_bf16(a, bQ[dc], c, 0, 0, 0);
            }
            __builtin_amdgcn_s_setprio(0);
            float p[16];
            #pragma unroll
            for (int r = 0; r < 16; r++) p[r] = fast_exp2(c[r]);
            l_run += ((p[0] + p[1]) + (p[2] + p[3])) + ((p[4] + p[5]) + (p[6] + p[7]))
                   + ((p[8] + p[9]) + (p[10] + p[11])) + ((p[12] + p[13]) + (p[14] + p[15]));
            union { unsigned u[4]; short8 s; } bP[2];
            #pragma unroll
            for (int kc2 = 0; kc2 < 2; kc2++) {
                int rb = kc2 * 8;
                unsigned A0 = pack2bf(p[rb + 0], p[rb + 1]);
                unsigned B0 = pack2bf(p[rb + 4], p[rb + 5]);
                unsigned A1 = pack2bf(p[rb + 2], p[rb + 3]);
                unsigned B1 = pack2bf(p[rb + 6], p[rb + 7]);
                uint2v s0 = __builtin_amdgcn_permlane32_swap(A0, B0, false, false);
                uint2v s1 = __builtin_amdgcn_permlane32_swap(A1, B1, false, false);
                bP[kc2].u[0] = s0[0];
                bP[kc2].u[1] = s1[0];
                bP[kc2].u[2] = s0[1];
                bP[kc2].u[3] = s1[1];
            }
            __builtin_amdgcn_s_setprio(1);
            #pragma unroll
            for (int eh = 0; eh < 2; eh++)
                #pragma unroll
                for (int kc2 = 0; kc2 < 2; kc2++) {
                    short8 av = *(const short8*)(VsC + ldoff[eh][kh * 2 + kc2]);
                    Oa[eh] = __builtin_amdgcn_mfma_f32_32x32x16_bf16(av, bP[kc2].s, Oa[eh], 0, 0, 0);
                }
            __builtin_amdgcn_s_setprio(0);
        }
    }

    // normalize + store: e = (r&3) + 8*(r>>2) + 4*hi + 32*eh
    float l = l_run + __shfl_xor(l_run, 32);
    float inv = 1.0f / l;
    unsigned short* op = Obf + ((size_t)n * LEN + l0 + col) * CH + h * HD + hi * 4;
    #pragma unroll
    for (int eh = 0; eh < 2; eh++)
        #pragma unroll
        for (int rq = 0; rq < 4; rq++) {
            int r = rq * 4;
            uint2 pk;
            pk.x = pack2bf(Oa[eh][r + 0] * inv, Oa[eh][r + 1] * inv);
            pk.y = pack2bf(Oa[eh][r + 2] * inv, Oa[eh][r + 3] * inv);
            *(uint2*)(op + eh * 32 + rq * 8) = pk;
        }
}

// ---------------------------------------------------------------------------
extern "C" void kernel_launch(void* const* d_in, const int* in_sizes, int n_in,
                              void* d_out, int out_size, void* d_ws, size_t ws_size,
                              hipStream_t stream)
{
    const float* x  = (const float*)d_in[0];
    const float* Wq = (const float*)d_in[1];
    const float* bq = (const float*)d_in[2];
    const float* Wk = (const float*)d_in[3];
    const float* bk = (const float*)d_in[4];
    const float* Wv = (const float*)d_in[5];
    const float* bv = (const float*)d_in[6];
    const float* Wo = (const float*)d_in[7];
    const float* bo = (const float*)d_in[8];
    const float* Wa = (const float*)d_in[9];
    const float* g1 = (const float*)d_in[10];
    const float* b1 = (const float*)d_in[11];
    const float* m1 = (const float*)d_in[12];
    const float* v1 = (const float*)d_in[13];
    const float* g2 = (const float*)d_in[14];
    const float* b2 = (const float*)d_in[15];
    const float* m2 = (const float*)d_in[16];
    const float* v2 = (const float*)d_in[17];

    float* wsf      = (float*)d_ws;
    float* bn_scale = wsf;            // 256
    float* bn_shift = wsf + 256;      // 256
    float* bkv      = wsf + 512;      // 512
    unsigned short* Wbf   = (unsigned short*)(wsf + 1024);          // 5*65536
    unsigned short* xbf   = Wbf + 5 * 65536;                        // [N,L,C]
    unsigned short* poolT = xbf   + (size_t)NBATCH * LEN * CH;      // [N,L2,C]
    unsigned short* xabf  = poolT + (size_t)NBATCH * LPOOL * CH;    // [N,L2,C]
    unsigned short* Kbf   = xabf  + (size_t)NBATCH * LPOOL * CH;    // [N,L2,C]
    unsigned short* Vbf   = Kbf   + (size_t)NBATCH * LPOOL * CH;    // [N,C,L2]
    unsigned short* Qbf   = Vbf   + (size_t)NBATCH * LPOOL * CH;    // [N,L,C]
    unsigned short* Obf   = Qbf   + (size_t)NBATCH * LEN * CH;      // [N,L,C]

    // 1. transpose+pool over x, weights->bf16, BN affine, bkv concat
    transpool_setup<<<1345, 256, 0, stream>>>(x, xbf, poolT,
        Wq, Wk, Wv, Wo, Wa, Wbf,
        g1, b1, m1, v1, g2, b2, m2, v2, bn_scale, bn_shift, bk, bv, bkv);

    // 2. q = Wq @ x + bq, pre-scaled by log2(e)/8 -> Qbf [N,L,C]
    gemm_mfma<<<dim3(64, 4, 4), 256, 0, stream>>>(
        Wbf + 0 * 65536, xbf, (size_t)LEN * CH, bq, nullptr, nullptr,
        nullptr, 0, Qbf, (size_t)LEN * CH, 256, nullptr, 0, 0, 1 << 30,
        LEN, 0.18033688f);

    // 3. xa = BN2(BN1(Wa @ pool(x))) -> xabf [N,L2,C]
    gemm_mfma<<<dim3(16, 4, 4), 256, 0, stream>>>(
        Wbf + 4 * 65536, poolT, (size_t)LPOOL * CH, nullptr, bn_scale, bn_shift,
        nullptr, 0, xabf, (size_t)LPOOL * CH, 256, nullptr, 0, 0, 1 << 30,
        LPOOL, 1.0f);

    // 4. fused k+v: A = [Wk;Wv] (contiguous in Wbf), M=512.
    //    rows 0..255 -> Kbf [l2][c] (mode1); rows 256..511 -> Vbf [c][l2] (mode2)
    gemm_mfma<<<dim3(16, 8, 4), 256, 0, stream>>>(
        Wbf + 1 * 65536, xabf, (size_t)LPOOL * CH, bkv, nullptr, nullptr,
        nullptr, 0, Kbf, (size_t)LPOOL * CH, 256, Vbf, (size_t)LPOOL * CH, LPOOL, 256,
        LPOOL, 1.0f);

    // 5. attention -> Obf [N,L,C] bf16
    //    (128-q blocks, 32 q/wave, async-DMA double-buffered K/V tiles)
    attn_mfma<<<dim3(LEN / 128, NH, NBATCH), 256, 0, stream>>>(Qbf, Kbf, Vbf, Obf);

    // 6. out = Wo @ o + bo -> f32 d_out [N,C,L]
    gemm_mfma<<<dim3(64, 4, 4), 256, 0, stream>>>(
        Wbf + 3 * 65536, Obf, (size_t)LEN * CH, bo, nullptr, nullptr,
        (float*)d_out, (size_t)CH * LEN, nullptr, 0, 0, nullptr, 0, 0, 1 << 30,
        LEN, 1.0f);
}